// Round 1
// baseline (2749.398 us; speedup 1.0000x reference)
//
#include <hip/hip_runtime.h>
#include <hip/hip_bf16.h>

constexpr int N_NODES  = 50000;
constexpr int N_EDGES  = 400000;
constexpr int EDGE_DIM = 144;
constexpr int HEADS    = 16;
constexpr int HEAD_DIM = 32;
constexpr int OUTD     = 512;   // HEADS*HEAD_DIM
constexpr int HID      = 64;
constexpr int NES      = 16;    // edge scalars feeding K-MLP
constexpr int NNS      = 64;    // node scalars feeding Q-MLP
#define ISQRTD 0.17677669529663687f

__device__ __forceinline__ float silu_f(float x) {
    return x / (1.0f + __expf(-x));
}

// monotonic float<->uint encoding for atomicMax over signed floats
__device__ __forceinline__ unsigned fenc(float f) {
    unsigned u = __float_as_uint(f);
    return (u & 0x80000000u) ? ~u : (u | 0x80000000u);
}
__device__ __forceinline__ float fdec(unsigned m) {
    unsigned u = (m & 0x80000000u) ? (m ^ 0x80000000u) : ~m;
    return __uint_as_float(u);
}

__device__ __forceinline__ void storeQ(float* p, float v) { *p = v; }
__device__ __forceinline__ void storeQ(__hip_bfloat16* p, float v) { *p = __float2bfloat16(v); }
__device__ __forceinline__ float loadQ(const float* p) { return *p; }
__device__ __forceinline__ float loadQ(const __hip_bfloat16* p) { return __bfloat162float(*p); }

// -------- kernel 0: zero out / denom / segmax --------------------------------
__global__ __launch_bounds__(256) void init_kernel(float* __restrict__ out,
                                                   float* __restrict__ denom,
                                                   unsigned* __restrict__ segmax) {
    int t = blockIdx.x * 256 + threadIdx.x;
    if (t < N_NODES * EDGE_DIM) out[t] = 0.0f;
    if (t < N_NODES * HEADS) {
        denom[t]  = 0.0f;
        segmax[t] = 0u;   // fdec(0) is below every finite encoded float
    }
}

// -------- kernel 1: Q-MLP per node (wave per node, 4 nodes/block) ------------
template <typename QT>
__global__ __launch_bounds__(256) void qmlp_kernel(
    const float* __restrict__ node_attrs,
    const float* __restrict__ w1, const float* __restrict__ b1,
    const float* __restrict__ w2, const float* __restrict__ b2,
    const float* __restrict__ w3, const float* __restrict__ b3,
    QT* __restrict__ qn) {
    __shared__ float xs[4][NNS];
    __shared__ float hs[4][HID];
    const int wid  = threadIdx.x >> 6;
    const int lane = threadIdx.x & 63;
    const int node = blockIdx.x * 4 + wid;
    const bool act = node < N_NODES;

    xs[wid][lane] = act ? node_attrs[(size_t)node * NNS + lane] : 0.0f;
    __syncthreads();

    float a = b1[lane];
    #pragma unroll
    for (int i = 0; i < NNS; ++i) a += xs[wid][i] * w1[i * HID + lane];
    a = silu_f(a);
    hs[wid][lane] = a;
    __syncthreads();

    float a2 = b2[lane];
    #pragma unroll
    for (int i = 0; i < HID; ++i) a2 += hs[wid][i] * w2[i * HID + lane];
    a2 = silu_f(a2);
    __syncthreads();          // all layer-2 reads of hs done (per-wave anyway)
    xs[wid][lane] = a2;       // reuse xs as h2
    __syncthreads();

    if (act) {
        #pragma unroll 1
        for (int j8 = 0; j8 < 8; ++j8) {
            const int col = j8 * 64 + lane;
            float acc = b3[col];
            #pragma unroll
            for (int i = 0; i < HID; ++i) acc += xs[wid][i] * w3[i * OUTD + col];
            storeQ(qn + (size_t)node * OUTD + col, acc);
        }
    }
}

// -------- kernel 2: K-MLP per edge + W = (K·Q)/sqrt(d) + segment max ---------
template <typename QT>
__global__ __launch_bounds__(256) void kmlp_kernel(
    const int* __restrict__ center, const float* __restrict__ edge_feat,
    const float* __restrict__ w1, const float* __restrict__ b1,
    const float* __restrict__ w2, const float* __restrict__ b2,
    const float* __restrict__ w3, const float* __restrict__ b3,
    const QT* __restrict__ qn, float* __restrict__ Wbuf,
    unsigned* __restrict__ segmax) {
    const int e = blockIdx.x * 256 + threadIdx.x;
    if (e >= N_EDGES) return;
    const int c = center[e];

    float x[NES];
    const float4* ef4 = reinterpret_cast<const float4*>(edge_feat + (size_t)e * EDGE_DIM);
    #pragma unroll
    for (int i = 0; i < NES / 4; ++i) {
        float4 t = ef4[i];
        x[4 * i + 0] = t.x; x[4 * i + 1] = t.y; x[4 * i + 2] = t.z; x[4 * i + 3] = t.w;
    }

    // layer 1: 16 -> 64 (fully unrolled so h1[] stays in registers)
    float h1[HID];
    #pragma unroll
    for (int j = 0; j < HID; ++j) {
        float a0 = 0.f, a1 = 0.f, a2 = 0.f, a3 = 0.f;
        #pragma unroll
        for (int i = 0; i < NES; i += 4) {
            a0 += x[i + 0] * w1[(i + 0) * HID + j];
            a1 += x[i + 1] * w1[(i + 1) * HID + j];
            a2 += x[i + 2] * w1[(i + 2) * HID + j];
            a3 += x[i + 3] * w1[(i + 3) * HID + j];
        }
        h1[j] = silu_f(b1[j] + ((a0 + a1) + (a2 + a3)));
    }

    // layer 2: 64 -> 64
    float h2[HID];
    #pragma unroll
    for (int j = 0; j < HID; ++j) {
        float a0 = 0.f, a1 = 0.f, a2 = 0.f, a3 = 0.f;
        #pragma unroll
        for (int i = 0; i < HID; i += 4) {
            a0 += h1[i + 0] * w2[(i + 0) * HID + j];
            a1 += h1[i + 1] * w2[(i + 1) * HID + j];
            a2 += h1[i + 2] * w2[(i + 2) * HID + j];
            a3 += h1[i + 3] * w2[(i + 3) * HID + j];
        }
        h2[j] = silu_f(b2[j] + ((a0 + a1) + (a2 + a3)));
    }

    // layer 3 fused with Q dot: K_j = h2 . w3[:,j] + b3[j];  W_h = sum_j K_j Q_j
    const QT* q = qn + (size_t)c * OUTD;
    #pragma unroll 1
    for (int h = 0; h < HEADS; ++h) {
        float wacc = 0.0f;
        #pragma unroll 1
        for (int jj = 0; jj < HEAD_DIM; ++jj) {
            const int j = h * HEAD_DIM + jj;
            float a0 = 0.f, a1 = 0.f, a2 = 0.f, a3 = 0.f;
            #pragma unroll
            for (int i = 0; i < HID; i += 4) {
                a0 += h2[i + 0] * w3[(i + 0) * OUTD + j];
                a1 += h2[i + 1] * w3[(i + 1) * OUTD + j];
                a2 += h2[i + 2] * w3[(i + 2) * OUTD + j];
                a3 += h2[i + 3] * w3[(i + 3) * OUTD + j];
            }
            const float kv = b3[j] + ((a0 + a1) + (a2 + a3));
            wacc += kv * loadQ(q + j);
        }
        const float Wv = wacc * ISQRTD;
        Wbuf[(size_t)e * HEADS + h] = Wv;
        atomicMax(&segmax[c * HEADS + h], fenc(Wv));
    }
}

// -------- kernel 3: ex = exp(W - segmax), denom += ex ------------------------
__global__ __launch_bounds__(256) void ex_denom_kernel(
    const int* __restrict__ center, const unsigned* __restrict__ segmax,
    float* __restrict__ Wbuf, float* __restrict__ denom) {
    const int t = blockIdx.x * 256 + threadIdx.x;
    if (t >= N_EDGES * HEADS) return;
    const int e = t >> 4;
    const int h = t & 15;
    const int c = center[e];
    const float m  = fdec(segmax[c * HEADS + h]);
    const float ex = __expf(Wbuf[t] - m);
    Wbuf[t] = ex;                       // overwrite logits with exp
    atomicAdd(&denom[c * HEADS + h], ex);
}

// -------- kernel 4: weighted scatter to nodes --------------------------------
__global__ __launch_bounds__(256) void scatter_kernel(
    const int* __restrict__ center, const float* __restrict__ edge_feat,
    const float* __restrict__ exbuf, const float* __restrict__ denom,
    float* __restrict__ out) {
    const int t = blockIdx.x * 256 + threadIdx.x;
    if (t >= N_EDGES * EDGE_DIM) return;
    const int e   = t / EDGE_DIM;
    const int col = t - e * EDGE_DIM;
    // column -> head: [0,16) dim1, [16,64) dim3, [64,144) dim5
    const int h = (col < 16) ? col : ((col < 64) ? (col - 16) / 3 : (col - 64) / 5);
    const int c = center[e];
    const float attn = exbuf[(size_t)e * HEADS + h] / denom[c * HEADS + h];
    atomicAdd(out + (size_t)c * EDGE_DIM + col, edge_feat[t] * attn);
}

extern "C" void kernel_launch(void* const* d_in, const int* in_sizes, int n_in,
                              void* d_out, int out_size, void* d_ws, size_t ws_size,
                              hipStream_t stream) {
    const int*   edge_index = (const int*)d_in[0];   // (2, E); row 0 = edge_center
    const float* edge_feat  = (const float*)d_in[1];
    const float* node_attrs = (const float*)d_in[2];
    const float* q_w1 = (const float*)d_in[3];
    const float* q_b1 = (const float*)d_in[4];
    const float* q_w2 = (const float*)d_in[5];
    const float* q_b2 = (const float*)d_in[6];
    const float* q_w3 = (const float*)d_in[7];
    const float* q_b3 = (const float*)d_in[8];
    const float* k_w1 = (const float*)d_in[9];
    const float* k_b1 = (const float*)d_in[10];
    const float* k_w2 = (const float*)d_in[11];
    const float* k_b2 = (const float*)d_in[12];
    const float* k_w3 = (const float*)d_in[13];
    const float* k_b3 = (const float*)d_in[14];
    const int* center = edge_index;                  // first E ints
    float* out = (float*)d_out;

    char* p = (char*)d_ws;
    float*    Wbuf   = (float*)p;    p += (size_t)N_EDGES * HEADS * sizeof(float);
    float*    denom  = (float*)p;    p += (size_t)N_NODES * HEADS * sizeof(float);
    unsigned* segmax = (unsigned*)p; p += (size_t)N_NODES * HEADS * sizeof(float);
    const size_t base = (size_t)(p - (char*)d_ws);
    const bool qf32 = ws_size >= base + (size_t)N_NODES * OUTD * sizeof(float);

    const int initGrid    = (N_NODES * EDGE_DIM + 255) / 256;           // 28125
    const int qmlpGrid    = (N_NODES + 3) / 4;                           // 12500
    const int kmlpGrid    = (N_EDGES + 255) / 256;                       // 1563
    const int exGrid      = (N_EDGES * HEADS + 255) / 256;               // 25000
    const int scatterGrid = (N_EDGES * EDGE_DIM + 255) / 256;            // 225000

    init_kernel<<<initGrid, 256, 0, stream>>>(out, denom, segmax);

    if (qf32) {
        float* qn = (float*)p;
        qmlp_kernel<float><<<qmlpGrid, 256, 0, stream>>>(
            node_attrs, q_w1, q_b1, q_w2, q_b2, q_w3, q_b3, qn);
        kmlp_kernel<float><<<kmlpGrid, 256, 0, stream>>>(
            center, edge_feat, k_w1, k_b1, k_w2, k_b2, k_w3, k_b3,
            qn, Wbuf, segmax);
    } else {
        __hip_bfloat16* qn = (__hip_bfloat16*)p;
        qmlp_kernel<__hip_bfloat16><<<qmlpGrid, 256, 0, stream>>>(
            node_attrs, q_w1, q_b1, q_w2, q_b2, q_w3, q_b3, qn);
        kmlp_kernel<__hip_bfloat16><<<kmlpGrid, 256, 0, stream>>>(
            center, edge_feat, k_w1, k_b1, k_w2, k_b2, k_w3, k_b3,
            qn, Wbuf, segmax);
    }

    ex_denom_kernel<<<exGrid, 256, 0, stream>>>(center, segmax, Wbuf, denom);
    scatter_kernel<<<scatterGrid, 256, 0, stream>>>(center, edge_feat, Wbuf, denom, out);
}

// Round 2
// 2582.305 us; speedup vs baseline: 1.0647x; 1.0647x over previous
//
#include <hip/hip_runtime.h>
#include <hip/hip_bf16.h>

constexpr int N_NODES  = 50000;
constexpr int N_EDGES  = 400000;
constexpr int EDGE_DIM = 144;
constexpr int HEADS    = 16;
constexpr int HEAD_DIM = 32;
constexpr int OUTD     = 512;   // HEADS*HEAD_DIM
constexpr int HID      = 64;
constexpr int NES      = 16;    // edge scalars feeding K-MLP
constexpr int NNS      = 64;    // node scalars feeding Q-MLP
#define ISQRTD 0.17677669529663687f

__device__ __forceinline__ float silu_f(float x) {
    return x / (1.0f + __expf(-x));
}

// monotonic float<->uint encoding for atomicMax over signed floats
__device__ __forceinline__ unsigned fenc(float f) {
    unsigned u = __float_as_uint(f);
    return (u & 0x80000000u) ? ~u : (u | 0x80000000u);
}
__device__ __forceinline__ float fdec(unsigned m) {
    unsigned u = (m & 0x80000000u) ? (m ^ 0x80000000u) : ~m;
    return __uint_as_float(u);
}

__device__ __forceinline__ void storeQ(float* p, float v) { *p = v; }
__device__ __forceinline__ void storeQ(__hip_bfloat16* p, float v) { *p = __float2bfloat16(v); }
__device__ __forceinline__ float loadQ(const float* p) { return *p; }
__device__ __forceinline__ float loadQ(const __hip_bfloat16* p) { return __bfloat162float(*p); }

__device__ __forceinline__ void loadP16(const float* p, float* o) {
    const float4* p4 = (const float4*)p;
    #pragma unroll
    for (int k = 0; k < 4; ++k) {
        float4 v = p4[k];
        o[4*k+0] = v.x; o[4*k+1] = v.y; o[4*k+2] = v.z; o[4*k+3] = v.w;
    }
}
__device__ __forceinline__ void loadP16(const __hip_bfloat16* p, float* o) {
    const uint4* p4 = (const uint4*)p;
    #pragma unroll
    for (int k = 0; k < 2; ++k) {
        uint4 v = p4[k];
        o[8*k+0] = __uint_as_float(v.x << 16);
        o[8*k+1] = __uint_as_float(v.x & 0xffff0000u);
        o[8*k+2] = __uint_as_float(v.y << 16);
        o[8*k+3] = __uint_as_float(v.y & 0xffff0000u);
        o[8*k+4] = __uint_as_float(v.z << 16);
        o[8*k+5] = __uint_as_float(v.z & 0xffff0000u);
        o[8*k+6] = __uint_as_float(v.w << 16);
        o[8*k+7] = __uint_as_float(v.w & 0xffff0000u);
    }
}

// -------- kernel P0: transpose k_w1 (16x64 -> 64x16) and k_w2 (64x64) --------
__global__ __launch_bounds__(256) void prep_kernel(
    const float* __restrict__ w1, const float* __restrict__ w2,
    float* __restrict__ w1T, float* __restrict__ w2T) {
    int t = blockIdx.x * 256 + threadIdx.x;
    if (t < NES * HID) {
        int i = t / HID, j = t % HID;
        w1T[j * NES + i] = w1[t];
    }
    if (t < HID * HID) {
        int i = t / HID, j = t % HID;
        w2T[j * HID + i] = w2[t];
    }
}

// -------- kernel 0: zero out / denom / segmax --------------------------------
__global__ __launch_bounds__(256) void init_kernel(float* __restrict__ out,
                                                   float* __restrict__ denom,
                                                   unsigned* __restrict__ segmax) {
    int t = blockIdx.x * 256 + threadIdx.x;
    if (t < N_NODES * EDGE_DIM) out[t] = 0.0f;
    if (t < N_NODES * HEADS) {
        denom[t]  = 0.0f;
        segmax[t] = 0u;   // below every finite encoded float
    }
}

// -------- kernel 1: Q-MLP per node (wave per node, 4 nodes/block) ------------
template <typename QT>
__global__ __launch_bounds__(256) void qmlp_kernel(
    const float* __restrict__ node_attrs,
    const float* __restrict__ w1, const float* __restrict__ b1,
    const float* __restrict__ w2, const float* __restrict__ b2,
    const float* __restrict__ w3, const float* __restrict__ b3,
    QT* __restrict__ qn) {
    __shared__ float xs[4][NNS];
    __shared__ float hs[4][HID];
    const int wid  = threadIdx.x >> 6;
    const int lane = threadIdx.x & 63;
    const int node = blockIdx.x * 4 + wid;
    const bool act = node < N_NODES;

    xs[wid][lane] = act ? node_attrs[(size_t)node * NNS + lane] : 0.0f;
    __syncthreads();

    float a = b1[lane];
    #pragma unroll
    for (int i = 0; i < NNS; ++i) a += xs[wid][i] * w1[i * HID + lane];
    a = silu_f(a);
    hs[wid][lane] = a;
    __syncthreads();

    float a2 = b2[lane];
    #pragma unroll
    for (int i = 0; i < HID; ++i) a2 += hs[wid][i] * w2[i * HID + lane];
    a2 = silu_f(a2);
    __syncthreads();
    xs[wid][lane] = a2;       // reuse xs as h2
    __syncthreads();

    if (act) {
        #pragma unroll 1
        for (int j8 = 0; j8 < 8; ++j8) {
            const int col = j8 * 64 + lane;
            float acc = b3[col];
            #pragma unroll
            for (int i = 0; i < HID; ++i) acc += xs[wid][i] * w3[i * OUTD + col];
            storeQ(qn + (size_t)node * OUTD + col, acc);
        }
    }
}

// -------- kernel 1b: P[n][i][h] = w3[i, h*32:+32] . Q[n, h*32:+32]; Sn ------
template <typename PT>
__global__ __launch_bounds__(256) void pcompute_kernel(
    const float* __restrict__ qn, const float* __restrict__ w3,
    const float* __restrict__ b3,
    PT* __restrict__ Pn, float* __restrict__ Sn) {
    const int h  = blockIdx.y;
    const int n0 = blockIdx.x * 64;
    __shared__ float w3s[64][33];   // +1 pad: avoids 4-way bank conflict on col reads
    {
        for (int ch = threadIdx.x; ch < 512; ch += 256) {
            const int i = ch >> 3, dg = ch & 7;
            const float4 v = *(const float4*)(w3 + (size_t)i * OUTD + h * HEAD_DIM + dg * 4);
            w3s[i][dg*4+0] = v.x; w3s[i][dg*4+1] = v.y;
            w3s[i][dg*4+2] = v.z; w3s[i][dg*4+3] = v.w;
        }
    }
    __syncthreads();
    const int nn = threadIdx.x >> 2;
    const int ig = threadIdx.x & 3;
    const int n  = n0 + nn;
    if (n >= N_NODES) return;

    float q[HEAD_DIM];
    const float4* q4 = (const float4*)(qn + (size_t)n * OUTD + h * HEAD_DIM);
    #pragma unroll
    for (int k = 0; k < 8; ++k) {
        float4 v = q4[k];
        q[4*k+0] = v.x; q[4*k+1] = v.y; q[4*k+2] = v.z; q[4*k+3] = v.w;
    }

    PT* prow = Pn + (size_t)n * (HID * HEADS) + h;
    #pragma unroll 4
    for (int ii = 0; ii < 16; ++ii) {
        const int i = ig * 16 + ii;
        float acc = 0.0f;
        #pragma unroll
        for (int d = 0; d < HEAD_DIM; ++d) acc += w3s[i][d] * q[d];
        storeQ(prow + (size_t)i * HEADS, acc);
    }
    if (ig == 0) {
        float s = 0.0f;
        #pragma unroll
        for (int d = 0; d < HEAD_DIM; ++d) s += b3[h * HEAD_DIM + d] * q[d];
        Sn[(size_t)n * HEADS + h] = s;
    }
}

// -------- kernel 2: K-MLP layers 1-2 + W = (h2.P + s)*isqrtd + seg max -------
template <typename PT>
__global__ __launch_bounds__(256) void wpass_kernel(
    const int* __restrict__ center, const float* __restrict__ edge_feat,
    const float* __restrict__ w1T, const float* __restrict__ b1,
    const float* __restrict__ w2T, const float* __restrict__ b2,
    const PT* __restrict__ Pn, const float* __restrict__ Sn,
    float* __restrict__ Wbuf, unsigned* __restrict__ segmax) {
    const int e = blockIdx.x * 256 + threadIdx.x;
    if (e >= N_EDGES) return;
    const int c = center[e];

    float x[NES];
    const float4* ef4 = reinterpret_cast<const float4*>(edge_feat + (size_t)e * EDGE_DIM);
    #pragma unroll
    for (int i = 0; i < NES / 4; ++i) {
        float4 t = ef4[i];
        x[4*i+0] = t.x; x[4*i+1] = t.y; x[4*i+2] = t.z; x[4*i+3] = t.w;
    }

    // layer 1: 16 -> 64, w1T rows contiguous (uniform s_load stream)
    float h1[HID];
    #pragma unroll
    for (int j = 0; j < HID; ++j) {
        float a = b1[j];
        #pragma unroll
        for (int i = 0; i < NES; ++i) a += x[i] * w1T[j * NES + i];
        h1[j] = silu_f(a);
    }

    // W accumulators seeded with s[c,h] = b3_h . Q_h
    float wacc[HEADS];
    {
        const float4* s4 = (const float4*)(Sn + (size_t)c * HEADS);
        #pragma unroll
        for (int k = 0; k < 4; ++k) {
            float4 v = s4[k];
            wacc[4*k+0] = v.x; wacc[4*k+1] = v.y; wacc[4*k+2] = v.z; wacc[4*k+3] = v.w;
        }
    }

    // layer 2 fused with W: h2_j = silu(b2_j + h1 . w2T[j]); wacc += h2_j * P[c][j][:]
    const PT* prow = Pn + (size_t)c * (HID * HEADS);
    #pragma unroll 2
    for (int j = 0; j < HID; ++j) {
        float a = b2[j];
        #pragma unroll
        for (int i = 0; i < HID; ++i) a += h1[i] * w2T[j * HID + i];
        const float h2 = silu_f(a);
        float p[HEADS];
        loadP16(prow + j * HEADS, p);
        #pragma unroll
        for (int hh = 0; hh < HEADS; ++hh) wacc[hh] += h2 * p[hh];
    }

    #pragma unroll
    for (int hh = 0; hh < HEADS; ++hh) {
        const float Wv = wacc[hh] * ISQRTD;
        Wbuf[(size_t)e * HEADS + hh] = Wv;
        atomicMax(&segmax[c * HEADS + hh], fenc(Wv));
    }
}

// -------- fallback kernel (round-1 kmlp, used only if ws too small) ----------
template <typename QT>
__global__ __launch_bounds__(256) void kmlp_kernel(
    const int* __restrict__ center, const float* __restrict__ edge_feat,
    const float* __restrict__ w1, const float* __restrict__ b1,
    const float* __restrict__ w2, const float* __restrict__ b2,
    const float* __restrict__ w3, const float* __restrict__ b3,
    const QT* __restrict__ qn, float* __restrict__ Wbuf,
    unsigned* __restrict__ segmax) {
    const int e = blockIdx.x * 256 + threadIdx.x;
    if (e >= N_EDGES) return;
    const int c = center[e];

    float x[NES];
    const float4* ef4 = reinterpret_cast<const float4*>(edge_feat + (size_t)e * EDGE_DIM);
    #pragma unroll
    for (int i = 0; i < NES / 4; ++i) {
        float4 t = ef4[i];
        x[4*i+0] = t.x; x[4*i+1] = t.y; x[4*i+2] = t.z; x[4*i+3] = t.w;
    }
    float h1[HID];
    #pragma unroll
    for (int j = 0; j < HID; ++j) {
        float a = 0.f;
        #pragma unroll
        for (int i = 0; i < NES; ++i) a += x[i] * w1[i * HID + j];
        h1[j] = silu_f(b1[j] + a);
    }
    float h2[HID];
    #pragma unroll
    for (int j = 0; j < HID; ++j) {
        float a = 0.f;
        #pragma unroll
        for (int i = 0; i < HID; ++i) a += h1[i] * w2[i * HID + j];
        h2[j] = silu_f(b2[j] + a);
    }
    const QT* q = qn + (size_t)c * OUTD;
    #pragma unroll 1
    for (int h = 0; h < HEADS; ++h) {
        float wacc = 0.0f;
        #pragma unroll 1
        for (int jj = 0; jj < HEAD_DIM; ++jj) {
            const int j = h * HEAD_DIM + jj;
            float a = 0.f;
            #pragma unroll
            for (int i = 0; i < HID; ++i) a += h2[i] * w3[i * OUTD + j];
            wacc += (b3[j] + a) * loadQ(q + j);
        }
        const float Wv = wacc * ISQRTD;
        Wbuf[(size_t)e * HEADS + h] = Wv;
        atomicMax(&segmax[c * HEADS + h], fenc(Wv));
    }
}

// -------- kernel 3: ex = exp(W - segmax), denom += ex ------------------------
__global__ __launch_bounds__(256) void ex_denom_kernel(
    const int* __restrict__ center, const unsigned* __restrict__ segmax,
    float* __restrict__ Wbuf, float* __restrict__ denom) {
    const int t = blockIdx.x * 256 + threadIdx.x;
    if (t >= N_EDGES * HEADS) return;
    const int e = t >> 4;
    const int h = t & 15;
    const int c = center[e];
    const float m  = fdec(segmax[c * HEADS + h]);
    const float ex = __expf(Wbuf[t] - m);
    Wbuf[t] = ex;
    atomicAdd(&denom[c * HEADS + h], ex);
}

// -------- kernel 3b: attn = ex / denom (in place) ----------------------------
__global__ __launch_bounds__(256) void attn_kernel(
    const int* __restrict__ center, float* __restrict__ Wbuf,
    const float* __restrict__ denom) {
    const int t = blockIdx.x * 256 + threadIdx.x;
    if (t >= N_EDGES * HEADS) return;
    const int e = t >> 4;
    const int h = t & 15;
    Wbuf[t] = Wbuf[t] / denom[center[e] * HEADS + h];
}

// -------- kernel 4: weighted scatter (float4 per thread) ---------------------
__global__ __launch_bounds__(256) void scatter4_kernel(
    const int* __restrict__ center, const float* __restrict__ edge_feat,
    const float* __restrict__ attn, float* __restrict__ out) {
    const int t = blockIdx.x * 256 + threadIdx.x;
    if (t >= N_EDGES * (EDGE_DIM / 4)) return;
    const int e  = t / (EDGE_DIM / 4);
    const int cg = t - e * (EDGE_DIM / 4);
    const int c  = center[e];
    const float4 f = *(const float4*)(edge_feat + (size_t)e * EDGE_DIM + cg * 4);
    const float* arow = attn + (size_t)e * HEADS;
    const float vals[4] = {f.x, f.y, f.z, f.w};
    #pragma unroll
    for (int k = 0; k < 4; ++k) {
        const int col = cg * 4 + k;
        const int h = (col < 16) ? col : ((col < 64) ? (col - 16) / 3 : (col - 64) / 5);
        atomicAdd(out + (size_t)c * EDGE_DIM + col, vals[k] * arow[h]);
    }
}

extern "C" void kernel_launch(void* const* d_in, const int* in_sizes, int n_in,
                              void* d_out, int out_size, void* d_ws, size_t ws_size,
                              hipStream_t stream) {
    const int*   edge_index = (const int*)d_in[0];
    const float* edge_feat  = (const float*)d_in[1];
    const float* node_attrs = (const float*)d_in[2];
    const float* q_w1 = (const float*)d_in[3];
    const float* q_b1 = (const float*)d_in[4];
    const float* q_w2 = (const float*)d_in[5];
    const float* q_b2 = (const float*)d_in[6];
    const float* q_w3 = (const float*)d_in[7];
    const float* q_b3 = (const float*)d_in[8];
    const float* k_w1 = (const float*)d_in[9];
    const float* k_b1 = (const float*)d_in[10];
    const float* k_w2 = (const float*)d_in[11];
    const float* k_b2 = (const float*)d_in[12];
    const float* k_w3 = (const float*)d_in[13];
    const float* k_b3 = (const float*)d_in[14];
    const int* center = edge_index;
    float* out = (float*)d_out;

    const size_t szQ    = (size_t)N_NODES * OUTD * sizeof(float);          // 102.4 MB
    const size_t szPf   = (size_t)N_NODES * HID * HEADS * sizeof(float);   // 204.8 MB
    const size_t szPb   = szPf / 2;                                        // 102.4 MB
    const size_t szS    = (size_t)N_NODES * HEADS * sizeof(float);         //   3.2 MB
    const size_t szW    = (size_t)N_EDGES * HEADS * sizeof(float);         //  25.6 MB
    const size_t szDen  = (size_t)N_NODES * HEADS * sizeof(float);
    const size_t szT    = (NES * HID + HID * HID) * sizeof(float);         //  20 KB

    const int initGrid    = (N_NODES * EDGE_DIM + 255) / 256;
    const int qmlpGrid    = (N_NODES + 3) / 4;
    const int edgeGrid    = (N_EDGES + 255) / 256;
    const int ehGrid      = (N_EDGES * HEADS + 255) / 256;
    const int scatterGrid = (N_EDGES * (EDGE_DIM / 4) + 255) / 256;
    const dim3 pGrid((N_NODES + 63) / 64, HEADS);

    const bool pathF32  = ws_size >= szQ + szPf + szS + szT;
    const bool pathBf16 = ws_size >= szQ + szPb + szS + szT;

    if (pathF32 || pathBf16) {
        // Layout: [Qn | Pn | Sn | w1T | w2T]; after pcompute, Qn region is
        // reused for Wbuf/denom/segmax (init launched AFTER pcompute).
        char* base = (char*)d_ws;
        float* Qn = (float*)base;
        char* pP  = base + szQ;
        const size_t szP = pathF32 ? szPf : szPb;
        char* pS  = pP + szP;
        float* Sn  = (float*)pS;
        float* w1T = (float*)(pS + szS);
        float* w2T = w1T + NES * HID;

        float*    Wbuf   = (float*)base;                 // aliases Qn
        float*    denom  = (float*)(base + szW);
        unsigned* segmax = (unsigned*)(base + szW + szDen);

        prep_kernel<<<16, 256, 0, stream>>>(k_w1, k_w2, w1T, w2T);
        qmlp_kernel<float><<<qmlpGrid, 256, 0, stream>>>(
            node_attrs, q_w1, q_b1, q_w2, q_b2, q_w3, q_b3, Qn);

        if (pathF32) {
            float* Pn = (float*)pP;
            pcompute_kernel<float><<<pGrid, 256, 0, stream>>>(Qn, k_w3, k_b3, Pn, Sn);
            init_kernel<<<initGrid, 256, 0, stream>>>(out, denom, segmax);
            wpass_kernel<float><<<edgeGrid, 256, 0, stream>>>(
                center, edge_feat, w1T, k_b1, w2T, k_b2, Pn, Sn, Wbuf, segmax);
        } else {
            __hip_bfloat16* Pn = (__hip_bfloat16*)pP;
            pcompute_kernel<__hip_bfloat16><<<pGrid, 256, 0, stream>>>(Qn, k_w3, k_b3, Pn, Sn);
            init_kernel<<<initGrid, 256, 0, stream>>>(out, denom, segmax);
            wpass_kernel<__hip_bfloat16><<<edgeGrid, 256, 0, stream>>>(
                center, edge_feat, w1T, k_b1, w2T, k_b2, Pn, Sn, Wbuf, segmax);
        }

        ex_denom_kernel<<<ehGrid, 256, 0, stream>>>(center, segmax, Wbuf, denom);
        attn_kernel<<<ehGrid, 256, 0, stream>>>(center, Wbuf, denom);
        scatter4_kernel<<<scatterGrid, 256, 0, stream>>>(center, edge_feat, Wbuf, out);
        return;
    }

    // ---------------- fallback: round-1 pipeline (small ws) ------------------
    char* p = (char*)d_ws;
    float*    Wbuf   = (float*)p;    p += szW;
    float*    denom  = (float*)p;    p += szDen;
    unsigned* segmax = (unsigned*)p; p += szDen;
    const size_t fbase = (size_t)(p - (char*)d_ws);
    const bool qf32 = ws_size >= fbase + szQ;

    init_kernel<<<initGrid, 256, 0, stream>>>(out, denom, segmax);
    if (qf32) {
        float* qn = (float*)p;
        qmlp_kernel<float><<<qmlpGrid, 256, 0, stream>>>(
            node_attrs, q_w1, q_b1, q_w2, q_b2, q_w3, q_b3, qn);
        kmlp_kernel<float><<<edgeGrid, 256, 0, stream>>>(
            center, edge_feat, k_w1, k_b1, k_w2, k_b2, k_w3, k_b3, qn, Wbuf, segmax);
    } else {
        __hip_bfloat16* qn = (__hip_bfloat16*)p;
        qmlp_kernel<__hip_bfloat16><<<qmlpGrid, 256, 0, stream>>>(
            node_attrs, q_w1, q_b1, q_w2, q_b2, q_w3, q_b3, qn);
        kmlp_kernel<__hip_bfloat16><<<edgeGrid, 256, 0, stream>>>(
            center, edge_feat, k_w1, k_b1, k_w2, k_b2, k_w3, k_b3, qn, Wbuf, segmax);
    }
    ex_denom_kernel<<<ehGrid, 256, 0, stream>>>(center, segmax, Wbuf, denom);
    attn_kernel<<<ehGrid, 256, 0, stream>>>(center, Wbuf, denom);
    scatter4_kernel<<<scatterGrid, 256, 0, stream>>>(center, edge_feat, Wbuf, out);
}

// Round 3
// 1813.681 us; speedup vs baseline: 1.5159x; 1.4238x over previous
//
#include <hip/hip_runtime.h>
#include <hip/hip_bf16.h>

constexpr int N_NODES  = 50000;
constexpr int N_EDGES  = 400000;
constexpr int EDGE_DIM = 144;
constexpr int HEADS    = 16;
constexpr int HEAD_DIM = 32;
constexpr int OUTD     = 512;   // HEADS*HEAD_DIM
constexpr int HID      = 64;
constexpr int NES      = 16;    // edge scalars feeding K-MLP
constexpr int NNS      = 64;    // node scalars feeding Q-MLP
constexpr int SCAN_B   = 512;
constexpr int NSB      = (N_NODES + SCAN_B - 1) / SCAN_B;   // 98
#define ISQRTD 0.17677669529663687f

__device__ __forceinline__ float silu_f(float x) {
    return x / (1.0f + __expf(-x));
}

// monotonic float<->uint encoding for atomicMax over signed floats (fallback path)
__device__ __forceinline__ unsigned fenc(float f) {
    unsigned u = __float_as_uint(f);
    return (u & 0x80000000u) ? ~u : (u | 0x80000000u);
}
__device__ __forceinline__ float fdec(unsigned m) {
    unsigned u = (m & 0x80000000u) ? (m ^ 0x80000000u) : ~m;
    return __uint_as_float(u);
}

__device__ __forceinline__ int headOf(int col) {
    return (col < 16) ? col : ((col < 64) ? (col - 16) / 3 : (col - 64) / 5);
}

__device__ __forceinline__ void storeQ(float* p, float v) { *p = v; }
__device__ __forceinline__ void storeQ(__hip_bfloat16* p, float v) { *p = __float2bfloat16(v); }
__device__ __forceinline__ float loadQ(const float* p) { return *p; }
__device__ __forceinline__ float loadQ(const __hip_bfloat16* p) { return __bfloat162float(*p); }

__device__ __forceinline__ void loadP16(const float* p, float* o) {
    const float4* p4 = (const float4*)p;
    #pragma unroll
    for (int k = 0; k < 4; ++k) {
        float4 v = p4[k];
        o[4*k+0] = v.x; o[4*k+1] = v.y; o[4*k+2] = v.z; o[4*k+3] = v.w;
    }
}
__device__ __forceinline__ void loadP16(const __hip_bfloat16* p, float* o) {
    const uint4* p4 = (const uint4*)p;
    #pragma unroll
    for (int k = 0; k < 2; ++k) {
        uint4 v = p4[k];
        o[8*k+0] = __uint_as_float(v.x << 16);
        o[8*k+1] = __uint_as_float(v.x & 0xffff0000u);
        o[8*k+2] = __uint_as_float(v.y << 16);
        o[8*k+3] = __uint_as_float(v.y & 0xffff0000u);
        o[8*k+4] = __uint_as_float(v.z << 16);
        o[8*k+5] = __uint_as_float(v.z & 0xffff0000u);
        o[8*k+6] = __uint_as_float(v.w << 16);
        o[8*k+7] = __uint_as_float(v.w & 0xffff0000u);
    }
}

// -------- prep: transpose k_w1 (16x64 -> 64x16) and k_w2 (64x64) -------------
__global__ __launch_bounds__(256) void prep_kernel(
    const float* __restrict__ w1, const float* __restrict__ w2,
    float* __restrict__ w1T, float* __restrict__ w2T) {
    int t = blockIdx.x * 256 + threadIdx.x;
    if (t < NES * HID) {
        int i = t / HID, j = t % HID;
        w1T[j * NES + i] = w1[t];
    }
    if (t < HID * HID) {
        int i = t / HID, j = t % HID;
        w2T[j * HID + i] = w2[t];
    }
}

// -------- Q-MLP per node (wave per node, 4 nodes/block) ----------------------
template <typename QT>
__global__ __launch_bounds__(256) void qmlp_kernel(
    const float* __restrict__ node_attrs,
    const float* __restrict__ w1, const float* __restrict__ b1,
    const float* __restrict__ w2, const float* __restrict__ b2,
    const float* __restrict__ w3, const float* __restrict__ b3,
    QT* __restrict__ qn) {
    __shared__ float xs[4][NNS];
    __shared__ float hs[4][HID];
    const int wid  = threadIdx.x >> 6;
    const int lane = threadIdx.x & 63;
    const int node = blockIdx.x * 4 + wid;
    const bool act = node < N_NODES;

    xs[wid][lane] = act ? node_attrs[(size_t)node * NNS + lane] : 0.0f;
    __syncthreads();

    float a = b1[lane];
    #pragma unroll
    for (int i = 0; i < NNS; ++i) a += xs[wid][i] * w1[i * HID + lane];
    a = silu_f(a);
    hs[wid][lane] = a;
    __syncthreads();

    float a2 = b2[lane];
    #pragma unroll
    for (int i = 0; i < HID; ++i) a2 += hs[wid][i] * w2[i * HID + lane];
    a2 = silu_f(a2);
    __syncthreads();
    xs[wid][lane] = a2;       // reuse xs as h2
    __syncthreads();

    if (act) {
        #pragma unroll 1
        for (int j8 = 0; j8 < 8; ++j8) {
            const int col = j8 * 64 + lane;
            float acc = b3[col];
            #pragma unroll
            for (int i = 0; i < HID; ++i) acc += xs[wid][i] * w3[i * OUTD + col];
            storeQ(qn + (size_t)node * OUTD + col, acc);
        }
    }
}

// -------- P[n][i][h] = w3[i, h*32:+32] . Q[n, h*32:+32]; Sn = b3_h . Q_h -----
template <typename PT>
__global__ __launch_bounds__(256) void pcompute_kernel(
    const float* __restrict__ qn, const float* __restrict__ w3,
    const float* __restrict__ b3,
    PT* __restrict__ Pn, float* __restrict__ Sn) {
    const int h  = blockIdx.y;
    const int n0 = blockIdx.x * 64;
    __shared__ float w3s[64][33];
    {
        for (int ch = threadIdx.x; ch < 512; ch += 256) {
            const int i = ch >> 3, dg = ch & 7;
            const float4 v = *(const float4*)(w3 + (size_t)i * OUTD + h * HEAD_DIM + dg * 4);
            w3s[i][dg*4+0] = v.x; w3s[i][dg*4+1] = v.y;
            w3s[i][dg*4+2] = v.z; w3s[i][dg*4+3] = v.w;
        }
    }
    __syncthreads();
    const int nn = threadIdx.x >> 2;
    const int ig = threadIdx.x & 3;
    const int n  = n0 + nn;
    if (n >= N_NODES) return;

    float q[HEAD_DIM];
    const float4* q4 = (const float4*)(qn + (size_t)n * OUTD + h * HEAD_DIM);
    #pragma unroll
    for (int k = 0; k < 8; ++k) {
        float4 v = q4[k];
        q[4*k+0] = v.x; q[4*k+1] = v.y; q[4*k+2] = v.z; q[4*k+3] = v.w;
    }

    PT* prow = Pn + (size_t)n * (HID * HEADS) + h;
    #pragma unroll 4
    for (int ii = 0; ii < 16; ++ii) {
        const int i = ig * 16 + ii;
        float acc = 0.0f;
        #pragma unroll
        for (int d = 0; d < HEAD_DIM; ++d) acc += w3s[i][d] * q[d];
        storeQ(prow + (size_t)i * HEADS, acc);
    }
    if (ig == 0) {
        float s = 0.0f;
        #pragma unroll
        for (int d = 0; d < HEAD_DIM; ++d) s += b3[h * HEAD_DIM + d] * q[d];
        Sn[(size_t)n * HEADS + h] = s;
    }
}

// -------- W-pass: K-MLP layers 1-2 + W = (h2.P + s)*isqrtd (no atomics) ------
template <typename PT>
__global__ __launch_bounds__(256) void wpass_kernel(
    const int* __restrict__ center, const float* __restrict__ edge_feat,
    const float* __restrict__ w1T, const float* __restrict__ b1,
    const float* __restrict__ w2T, const float* __restrict__ b2,
    const PT* __restrict__ Pn, const float* __restrict__ Sn,
    float* __restrict__ Wbuf) {
    const int e = blockIdx.x * 256 + threadIdx.x;
    if (e >= N_EDGES) return;
    const int c = center[e];

    float x[NES];
    const float4* ef4 = reinterpret_cast<const float4*>(edge_feat + (size_t)e * EDGE_DIM);
    #pragma unroll
    for (int i = 0; i < NES / 4; ++i) {
        float4 t = ef4[i];
        x[4*i+0] = t.x; x[4*i+1] = t.y; x[4*i+2] = t.z; x[4*i+3] = t.w;
    }

    float h1[HID];
    #pragma unroll
    for (int j = 0; j < HID; ++j) {
        float a = b1[j];
        #pragma unroll
        for (int i = 0; i < NES; ++i) a += x[i] * w1T[j * NES + i];
        h1[j] = silu_f(a);
    }

    float wacc[HEADS];
    {
        const float4* s4 = (const float4*)(Sn + (size_t)c * HEADS);
        #pragma unroll
        for (int k = 0; k < 4; ++k) {
            float4 v = s4[k];
            wacc[4*k+0] = v.x; wacc[4*k+1] = v.y; wacc[4*k+2] = v.z; wacc[4*k+3] = v.w;
        }
    }

    const PT* prow = Pn + (size_t)c * (HID * HEADS);
    #pragma unroll 2
    for (int j = 0; j < HID; ++j) {
        float a = b2[j];
        #pragma unroll
        for (int i = 0; i < HID; ++i) a += h1[i] * w2T[j * HID + i];
        const float h2 = silu_f(a);
        float p[HEADS];
        loadP16(prow + j * HEADS, p);
        #pragma unroll
        for (int hh = 0; hh < HEADS; ++hh) wacc[hh] += h2 * p[hh];
    }

    float4* wrow = (float4*)(Wbuf + (size_t)e * HEADS);
    #pragma unroll
    for (int k = 0; k < 4; ++k) {
        wrow[k] = make_float4(wacc[4*k+0] * ISQRTD, wacc[4*k+1] * ISQRTD,
                              wacc[4*k+2] * ISQRTD, wacc[4*k+3] * ISQRTD);
    }
}

// -------- CSR build ----------------------------------------------------------
__global__ __launch_bounds__(256) void zero_counts_kernel(int* __restrict__ counts) {
    int t = blockIdx.x * 256 + threadIdx.x;
    if (t < N_NODES) counts[t] = 0;
}
__global__ __launch_bounds__(256) void hist_kernel(const int* __restrict__ center,
                                                   int* __restrict__ counts) {
    int e = blockIdx.x * 256 + threadIdx.x;
    if (e < N_EDGES) atomicAdd(&counts[center[e]], 1);
}
__global__ __launch_bounds__(SCAN_B) void scan1_kernel(
    const int* __restrict__ counts, int* __restrict__ incl, int* __restrict__ blockSums) {
    __shared__ int sm[SCAN_B];
    const int gid = blockIdx.x * SCAN_B + threadIdx.x;
    sm[threadIdx.x] = (gid < N_NODES) ? counts[gid] : 0;
    __syncthreads();
    #pragma unroll 1
    for (int off = 1; off < SCAN_B; off <<= 1) {
        int t = (threadIdx.x >= off) ? sm[threadIdx.x - off] : 0;
        __syncthreads();
        sm[threadIdx.x] += t;
        __syncthreads();
    }
    if (gid < N_NODES) incl[gid] = sm[threadIdx.x];
    if (threadIdx.x == SCAN_B - 1) blockSums[blockIdx.x] = sm[threadIdx.x];
}
__global__ void scan2_kernel(int* __restrict__ blockSums) {
    if (threadIdx.x == 0 && blockIdx.x == 0) {
        int run = 0;
        for (int i = 0; i < NSB; ++i) { int t = blockSums[i]; blockSums[i] = run; run += t; }
    }
}
__global__ __launch_bounds__(SCAN_B) void scan3_kernel(
    const int* __restrict__ counts, const int* __restrict__ incl,
    const int* __restrict__ blockSums, int* __restrict__ rowStart,
    int* __restrict__ cursor) {
    const int gid = blockIdx.x * SCAN_B + threadIdx.x;
    if (gid < N_NODES) {
        const int excl = incl[gid] - counts[gid] + blockSums[blockIdx.x];
        rowStart[gid] = excl;
        cursor[gid]   = excl;
    }
    if (gid == 0) rowStart[N_NODES] = N_EDGES;
}
__global__ __launch_bounds__(256) void fill_kernel(const int* __restrict__ center,
                                                   int* __restrict__ cursor,
                                                   int* __restrict__ edgeList) {
    int e = blockIdx.x * 256 + threadIdx.x;
    if (e < N_EDGES) {
        int pos = atomicAdd(&cursor[center[e]], 1);
        edgeList[pos] = e;
    }
}

// -------- node gather: softmax + weighted sum, atomic-free -------------------
__global__ __launch_bounds__(256) void gather_kernel(
    const int* __restrict__ rowStart, const int* __restrict__ edgeList,
    const float* __restrict__ edge_feat, const float* __restrict__ Wbuf,
    float* __restrict__ out) {
    const int wid  = threadIdx.x >> 6;
    const int lane = threadIdx.x & 63;
    const int n = blockIdx.x * 4 + wid;
    if (n >= N_NODES) return;
    const int rs = rowStart[n];
    const int d  = rowStart[n + 1] - rs;

    const int c0 = lane, c1 = lane + 64, c2 = lane + 128;
    const int h0 = headOf(c0);
    const int h1 = headOf(c1);
    const int h2 = (c2 < EDGE_DIM) ? headOf(c2) : 0;

    float acc0 = 0.f, acc1 = 0.f, acc2 = 0.f;
    if (d > 0) {
        const int hh  = lane & 15;     // stats head owned by this lane
        const int sub = lane >> 4;
        float m = -3.0e38f;
        for (int i = sub; i < d; i += 4)
            m = fmaxf(m, Wbuf[(size_t)edgeList[rs + i] * HEADS + hh]);
        m = fmaxf(m, __shfl_xor(m, 16));
        m = fmaxf(m, __shfl_xor(m, 32));
        float s = 0.f;
        for (int i = sub; i < d; i += 4)
            s += __expf(Wbuf[(size_t)edgeList[rs + i] * HEADS + hh] - m);
        s += __shfl_xor(s, 16);
        s += __shfl_xor(s, 32);
        const float rden = 1.0f / s;

        for (int i = 0; i < d; ++i) {
            const int e = edgeList[rs + i];
            const float aL = __expf(Wbuf[(size_t)e * HEADS + hh] - m) * rden;
            const float a0 = __shfl(aL, h0);
            const float a1 = __shfl(aL, h1);
            const float a2 = __shfl(aL, h2);
            const float* fr = edge_feat + (size_t)e * EDGE_DIM;
            acc0 += fr[c0] * a0;
            acc1 += fr[c1] * a1;
            if (c2 < EDGE_DIM) acc2 += fr[c2] * a2;
        }
    }
    float* orow = out + (size_t)n * EDGE_DIM;
    orow[c0] = acc0;
    orow[c1] = acc1;
    if (c2 < EDGE_DIM) orow[c2] = acc2;
}

// ==================== fallback-only kernels (small workspace) ================
__global__ __launch_bounds__(256) void init_kernel(float* __restrict__ out,
                                                   float* __restrict__ denom,
                                                   unsigned* __restrict__ segmax) {
    int t = blockIdx.x * 256 + threadIdx.x;
    if (t < N_NODES * EDGE_DIM) out[t] = 0.0f;
    if (t < N_NODES * HEADS) {
        denom[t]  = 0.0f;
        segmax[t] = 0u;
    }
}

template <typename QT>
__global__ __launch_bounds__(256) void kmlp_kernel(
    const int* __restrict__ center, const float* __restrict__ edge_feat,
    const float* __restrict__ w1, const float* __restrict__ b1,
    const float* __restrict__ w2, const float* __restrict__ b2,
    const float* __restrict__ w3, const float* __restrict__ b3,
    const QT* __restrict__ qn, float* __restrict__ Wbuf,
    unsigned* __restrict__ segmax) {
    const int e = blockIdx.x * 256 + threadIdx.x;
    if (e >= N_EDGES) return;
    const int c = center[e];

    float x[NES];
    const float4* ef4 = reinterpret_cast<const float4*>(edge_feat + (size_t)e * EDGE_DIM);
    #pragma unroll
    for (int i = 0; i < NES / 4; ++i) {
        float4 t = ef4[i];
        x[4*i+0] = t.x; x[4*i+1] = t.y; x[4*i+2] = t.z; x[4*i+3] = t.w;
    }
    float h1[HID];
    #pragma unroll
    for (int j = 0; j < HID; ++j) {
        float a = 0.f;
        #pragma unroll
        for (int i = 0; i < NES; ++i) a += x[i] * w1[i * HID + j];
        h1[j] = silu_f(b1[j] + a);
    }
    float h2[HID];
    #pragma unroll
    for (int j = 0; j < HID; ++j) {
        float a = 0.f;
        #pragma unroll
        for (int i = 0; i < HID; ++i) a += h1[i] * w2[i * HID + j];
        h2[j] = silu_f(b2[j] + a);
    }
    const QT* q = qn + (size_t)c * OUTD;
    #pragma unroll 1
    for (int h = 0; h < HEADS; ++h) {
        float wacc = 0.0f;
        #pragma unroll 1
        for (int jj = 0; jj < HEAD_DIM; ++jj) {
            const int j = h * HEAD_DIM + jj;
            float a = 0.f;
            #pragma unroll
            for (int i = 0; i < HID; ++i) a += h2[i] * w3[i * OUTD + j];
            wacc += (b3[j] + a) * loadQ(q + j);
        }
        const float Wv = wacc * ISQRTD;
        Wbuf[(size_t)e * HEADS + h] = Wv;
        atomicMax(&segmax[c * HEADS + h], fenc(Wv));
    }
}

__global__ __launch_bounds__(256) void ex_denom_kernel(
    const int* __restrict__ center, const unsigned* __restrict__ segmax,
    float* __restrict__ Wbuf, float* __restrict__ denom) {
    const int t = blockIdx.x * 256 + threadIdx.x;
    if (t >= N_EDGES * HEADS) return;
    const int e = t >> 4;
    const int h = t & 15;
    const int c = center[e];
    const float m  = fdec(segmax[c * HEADS + h]);
    const float ex = __expf(Wbuf[t] - m);
    Wbuf[t] = ex;
    atomicAdd(&denom[c * HEADS + h], ex);
}

__global__ __launch_bounds__(256) void attn_kernel(
    const int* __restrict__ center, float* __restrict__ Wbuf,
    const float* __restrict__ denom) {
    const int t = blockIdx.x * 256 + threadIdx.x;
    if (t >= N_EDGES * HEADS) return;
    const int e = t >> 4;
    const int h = t & 15;
    Wbuf[t] = Wbuf[t] / denom[center[e] * HEADS + h];
}

__global__ __launch_bounds__(256) void scatter4_kernel(
    const int* __restrict__ center, const float* __restrict__ edge_feat,
    const float* __restrict__ attn, float* __restrict__ out) {
    const int t = blockIdx.x * 256 + threadIdx.x;
    if (t >= N_EDGES * (EDGE_DIM / 4)) return;
    const int e  = t / (EDGE_DIM / 4);
    const int cg = t - e * (EDGE_DIM / 4);
    const int c  = center[e];
    const float4 f = *(const float4*)(edge_feat + (size_t)e * EDGE_DIM + cg * 4);
    const float* arow = attn + (size_t)e * HEADS;
    const float vals[4] = {f.x, f.y, f.z, f.w};
    #pragma unroll
    for (int k = 0; k < 4; ++k) {
        const int col = cg * 4 + k;
        const int h = headOf(col);
        atomicAdd(out + (size_t)c * EDGE_DIM + col, vals[k] * arow[h]);
    }
}

extern "C" void kernel_launch(void* const* d_in, const int* in_sizes, int n_in,
                              void* d_out, int out_size, void* d_ws, size_t ws_size,
                              hipStream_t stream) {
    const int*   edge_index = (const int*)d_in[0];
    const float* edge_feat  = (const float*)d_in[1];
    const float* node_attrs = (const float*)d_in[2];
    const float* q_w1 = (const float*)d_in[3];
    const float* q_b1 = (const float*)d_in[4];
    const float* q_w2 = (const float*)d_in[5];
    const float* q_b2 = (const float*)d_in[6];
    const float* q_w3 = (const float*)d_in[7];
    const float* q_b3 = (const float*)d_in[8];
    const float* k_w1 = (const float*)d_in[9];
    const float* k_b1 = (const float*)d_in[10];
    const float* k_w2 = (const float*)d_in[11];
    const float* k_b2 = (const float*)d_in[12];
    const float* k_w3 = (const float*)d_in[13];
    const float* k_b3 = (const float*)d_in[14];
    const int* center = edge_index;
    float* out = (float*)d_out;

    const size_t szQ    = (size_t)N_NODES * OUTD * sizeof(float);          // 102.4 MB
    const size_t szPf   = (size_t)N_NODES * HID * HEADS * sizeof(float);   // 204.8 MB
    const size_t szPb   = szPf / 2;                                        // 102.4 MB
    const size_t szS    = (size_t)N_NODES * HEADS * sizeof(float);         //   3.2 MB
    const size_t szW    = (size_t)N_EDGES * HEADS * sizeof(float);         //  25.6 MB
    const size_t szDen  = (size_t)N_NODES * HEADS * sizeof(float);
    const size_t szT    = (NES * HID + HID * HID) * sizeof(float);         //  20 KB

    const int qmlpGrid    = (N_NODES + 3) / 4;
    const int edgeGrid    = (N_EDGES + 255) / 256;
    const int nodeGrid256 = (N_NODES + 255) / 256;
    const int ehGrid      = (N_EDGES * HEADS + 255) / 256;
    const dim3 pGrid((N_NODES + 63) / 64, HEADS);

    const bool pathF32  = ws_size >= szQ + szPf + szS + szT;
    const bool pathBf16 = ws_size >= szQ + szPb + szS + szT;

    if (pathF32 || pathBf16) {
        // Layout: [Qn | Pn | Sn | w1T | w2T]. After pcompute, Qn region is
        // reused for [Wbuf | counts | incl | rowStart | cursor | blockSums | edgeList].
        char* base = (char*)d_ws;
        float* Qn = (float*)base;
        char* pP  = base + szQ;
        const size_t szP = pathF32 ? szPf : szPb;
        char* pS  = pP + szP;
        float* Sn  = (float*)pS;
        float* w1T = (float*)(pS + szS);
        float* w2T = w1T + NES * HID;

        float* Wbuf     = (float*)base;                      // aliases Qn (dead)
        int*   counts   = (int*)(base + szW);
        int*   incl     = counts + N_NODES;
        int*   rowStart = incl + N_NODES;                    // N_NODES+1
        int*   cursor   = rowStart + N_NODES + 1;
        int*   blockSums= cursor + N_NODES;
        int*   edgeList = blockSums + ((NSB + 63) & ~63);

        prep_kernel<<<16, 256, 0, stream>>>(k_w1, k_w2, w1T, w2T);
        qmlp_kernel<float><<<qmlpGrid, 256, 0, stream>>>(
            node_attrs, q_w1, q_b1, q_w2, q_b2, q_w3, q_b3, Qn);

        if (pathF32) {
            float* Pn = (float*)pP;
            pcompute_kernel<float><<<pGrid, 256, 0, stream>>>(Qn, k_w3, k_b3, Pn, Sn);
        } else {
            __hip_bfloat16* Pn = (__hip_bfloat16*)pP;
            pcompute_kernel<__hip_bfloat16><<<pGrid, 256, 0, stream>>>(Qn, k_w3, k_b3, Pn, Sn);
        }

        // CSR build (Qn now dead; alias region safe)
        zero_counts_kernel<<<nodeGrid256, 256, 0, stream>>>(counts);
        hist_kernel<<<edgeGrid, 256, 0, stream>>>(center, counts);
        scan1_kernel<<<NSB, SCAN_B, 0, stream>>>(counts, incl, blockSums);
        scan2_kernel<<<1, 64, 0, stream>>>(blockSums);
        scan3_kernel<<<NSB, SCAN_B, 0, stream>>>(counts, incl, blockSums, rowStart, cursor);
        fill_kernel<<<edgeGrid, 256, 0, stream>>>(center, cursor, edgeList);

        if (pathF32) {
            float* Pn = (float*)pP;
            wpass_kernel<float><<<edgeGrid, 256, 0, stream>>>(
                center, edge_feat, w1T, k_b1, w2T, k_b2, Pn, Sn, Wbuf);
        } else {
            __hip_bfloat16* Pn = (__hip_bfloat16*)pP;
            wpass_kernel<__hip_bfloat16><<<edgeGrid, 256, 0, stream>>>(
                center, edge_feat, w1T, k_b1, w2T, k_b2, Pn, Sn, Wbuf);
        }

        gather_kernel<<<qmlpGrid, 256, 0, stream>>>(rowStart, edgeList, edge_feat, Wbuf, out);
        return;
    }

    // ---------------- fallback: atomic pipeline (small ws) -------------------
    char* p = (char*)d_ws;
    float*    Wbuf   = (float*)p;    p += szW;
    float*    denom  = (float*)p;    p += szDen;
    unsigned* segmax = (unsigned*)p; p += szDen;
    const size_t fbase = (size_t)(p - (char*)d_ws);
    const bool qf32 = ws_size >= fbase + szQ;

    const int initGrid    = (N_NODES * EDGE_DIM + 255) / 256;
    const int scatterGrid = (N_EDGES * (EDGE_DIM / 4) + 255) / 256;

    init_kernel<<<initGrid, 256, 0, stream>>>(out, denom, segmax);
    if (qf32) {
        float* qn = (float*)p;
        qmlp_kernel<float><<<qmlpGrid, 256, 0, stream>>>(
            node_attrs, q_w1, q_b1, q_w2, q_b2, q_w3, q_b3, qn);
        kmlp_kernel<float><<<edgeGrid, 256, 0, stream>>>(
            center, edge_feat, k_w1, k_b1, k_w2, k_b2, k_w3, k_b3, qn, Wbuf, segmax);
    } else {
        __hip_bfloat16* qn = (__hip_bfloat16*)p;
        qmlp_kernel<__hip_bfloat16><<<qmlpGrid, 256, 0, stream>>>(
            node_attrs, q_w1, q_b1, q_w2, q_b2, q_w3, q_b3, qn);
        kmlp_kernel<__hip_bfloat16><<<edgeGrid, 256, 0, stream>>>(
            center, edge_feat, k_w1, k_b1, k_w2, k_b2, k_w3, k_b3, qn, Wbuf, segmax);
    }
    ex_denom_kernel<<<ehGrid, 256, 0, stream>>>(center, segmax, Wbuf, denom);
    attn_kernel<<<ehGrid, 256, 0, stream>>>(center, Wbuf, denom);
    scatter4_kernel<<<scatterGrid, 256, 0, stream>>>(center, edge_feat, Wbuf, out);
}

// Round 5
// 790.345 us; speedup vs baseline: 3.4787x; 2.2948x over previous
//
#include <hip/hip_runtime.h>
#include <hip/hip_bf16.h>

constexpr int N_NODES  = 50000;
constexpr int N_EDGES  = 400000;
constexpr int EDGE_DIM = 144;
constexpr int HEADS    = 16;
constexpr int HEAD_DIM = 32;
constexpr int OUTD     = 512;   // HEADS*HEAD_DIM
constexpr int HID      = 64;
constexpr int NES      = 16;
constexpr int NNS      = 64;
constexpr int SCAN_B   = 512;
constexpr int NSB      = (N_NODES + SCAN_B - 1) / SCAN_B;   // 98
constexpr int NPB_P    = 25;    // nodes per block, pcompute2 (50000 = 2000*25)
constexpr int NPB_Q    = 16;    // nodes per block, qmlp2    (50000 = 3125*16)
#define ISQRTD 0.17677669529663687f

__device__ __forceinline__ float silu_f(float x) {
    return x / (1.0f + __expf(-x));
}

__device__ __forceinline__ unsigned fenc(float f) {
    unsigned u = __float_as_uint(f);
    return (u & 0x80000000u) ? ~u : (u | 0x80000000u);
}
__device__ __forceinline__ float fdec(unsigned m) {
    unsigned u = (m & 0x80000000u) ? (m ^ 0x80000000u) : ~m;
    return __uint_as_float(u);
}

__device__ __forceinline__ int headOf(int col) {
    return (col < 16) ? col : ((col < 64) ? (col - 16) / 3 : (col - 64) / 5);
}

__device__ __forceinline__ unsigned short bf16bits(float v) {
    __hip_bfloat16 b = __float2bfloat16(v);
    return *reinterpret_cast<unsigned short*>(&b);
}

__device__ __forceinline__ void storeQ(float* p, float v) { *p = v; }
__device__ __forceinline__ void storeQ(__hip_bfloat16* p, float v) { *p = __float2bfloat16(v); }
__device__ __forceinline__ float loadQ(const float* p) { return *p; }
__device__ __forceinline__ float loadQ(const __hip_bfloat16* p) { return __bfloat162float(*p); }

__device__ __forceinline__ void storeP4(float* p, float4 v) { *(float4*)p = v; }
__device__ __forceinline__ void storeP4(__hip_bfloat16* p, float4 v) {
    ushort4 u;
    u.x = bf16bits(v.x); u.y = bf16bits(v.y);
    u.z = bf16bits(v.z); u.w = bf16bits(v.w);
    *(ushort4*)p = u;
}

__device__ __forceinline__ void loadP16(const float* p, float* o) {
    const float4* p4 = (const float4*)p;
    #pragma unroll
    for (int k = 0; k < 4; ++k) {
        float4 v = p4[k];
        o[4*k+0] = v.x; o[4*k+1] = v.y; o[4*k+2] = v.z; o[4*k+3] = v.w;
    }
}
__device__ __forceinline__ void loadP16(const __hip_bfloat16* p, float* o) {
    const uint4* p4 = (const uint4*)p;
    #pragma unroll
    for (int k = 0; k < 2; ++k) {
        uint4 v = p4[k];
        o[8*k+0] = __uint_as_float(v.x << 16);
        o[8*k+1] = __uint_as_float(v.x & 0xffff0000u);
        o[8*k+2] = __uint_as_float(v.y << 16);
        o[8*k+3] = __uint_as_float(v.y & 0xffff0000u);
        o[8*k+4] = __uint_as_float(v.z << 16);
        o[8*k+5] = __uint_as_float(v.z & 0xffff0000u);
        o[8*k+6] = __uint_as_float(v.w << 16);
        o[8*k+7] = __uint_as_float(v.w & 0xffff0000u);
    }
}

// -------- prep: transpose k_w1 (16x64 -> 64x16) and k_w2 (64x64) -------------
__global__ __launch_bounds__(256) void prep_kernel(
    const float* __restrict__ w1, const float* __restrict__ w2,
    float* __restrict__ w1T, float* __restrict__ w2T) {
    int t = blockIdx.x * 256 + threadIdx.x;
    if (t < NES * HID) {
        int i = t / HID, j = t % HID;
        w1T[j * NES + i] = w1[t];
    }
    if (t < HID * HID) {
        int i = t / HID, j = t % HID;
        w2T[j * HID + i] = w2[t];
    }
}

// -------- Q-MLP v2: layers 1-2 wave-per-node, layer 3 via persistent regs ----
__global__ __launch_bounds__(256) void qmlp2_kernel(
    const float* __restrict__ node_attrs,
    const float* __restrict__ w1, const float* __restrict__ b1,
    const float* __restrict__ w2, const float* __restrict__ b2,
    const float* __restrict__ w3, const float* __restrict__ b3,
    float* __restrict__ qn) {
    const int t    = threadIdx.x;
    const int wid  = t >> 6;
    const int lane = t & 63;
    const int n0   = blockIdx.x * NPB_Q;

    // persistent layer-3 weights: this thread owns cols t and t+256
    float w3a[HID], w3b[HID];
    #pragma unroll
    for (int i = 0; i < HID; ++i) {
        w3a[i] = w3[(size_t)i * OUTD + t];
        w3b[i] = w3[(size_t)i * OUTD + 256 + t];
    }

    __shared__ float xs[4][NNS];
    __shared__ float h1s[4][HID];
    __shared__ float h2s[NPB_Q][HID];

    #pragma unroll 1
    for (int r = 0; r < NPB_Q / 4; ++r) {
        const int n   = n0 + r * 4 + wid;
        const bool act = n < N_NODES;
        xs[wid][lane] = act ? node_attrs[(size_t)n * NNS + lane] : 0.0f;
        __syncthreads();
        float a = b1[lane];
        #pragma unroll
        for (int i = 0; i < NNS; ++i) a += xs[wid][i] * w1[i * HID + lane];
        h1s[wid][lane] = silu_f(a);
        __syncthreads();
        float a2 = b2[lane];
        #pragma unroll
        for (int i = 0; i < HID; ++i) a2 += h1s[wid][i] * w2[i * HID + lane];
        h2s[r * 4 + wid][lane] = silu_f(a2);
        __syncthreads();
    }

    #pragma unroll 1
    for (int m = 0; m < NPB_Q; ++m) {
        const int n = n0 + m;
        if (n >= N_NODES) break;
        float acc0 = b3[t], acc1 = b3[256 + t];
        #pragma unroll
        for (int i = 0; i < HID; ++i) {
            const float h = h2s[m][i];
            acc0 += h * w3a[i];
            acc1 += h * w3b[i];
        }
        qn[(size_t)n * OUTD + t]       = acc0;
        qn[(size_t)n * OUTD + 256 + t] = acc1;
    }
}

// -------- pcompute v2: persistent w3k regs, LDS-broadcast Q, coalesced store -
template <typename PT>
__global__ __launch_bounds__(256) void pcompute2_kernel(
    const float* __restrict__ qn, const float* __restrict__ w3,
    const float* __restrict__ b3,
    PT* __restrict__ Pn, float* __restrict__ Sn) {
    const int t   = threadIdx.x;
    const int i   = t >> 2;          // output row 0..63
    const int hb4 = (t & 3) * 4;     // first of 4 heads

    // 128 persistent weights: w3k[i][ (hb4+k)*32 + d ]
    float w3reg[4][HEAD_DIM];
    #pragma unroll
    for (int k = 0; k < 4; ++k) {
        const float4* src = (const float4*)(w3 + (size_t)i * OUTD + (hb4 + k) * HEAD_DIM);
        #pragma unroll
        for (int d4 = 0; d4 < 8; ++d4) {
            float4 v = src[d4];
            w3reg[k][d4*4+0] = v.x; w3reg[k][d4*4+1] = v.y;
            w3reg[k][d4*4+2] = v.z; w3reg[k][d4*4+3] = v.w;
        }
    }

    __shared__ float Qs[OUTD];
    __shared__ float b3s[OUTD];
    b3s[t]       = b3[t];
    b3s[t + 256] = b3[t + 256];

    const int n0 = blockIdx.x * NPB_P;
    #pragma unroll 1
    for (int m = 0; m < NPB_P; ++m) {
        const int n = n0 + m;
        const bool act = n < N_NODES;
        float2 qv = make_float2(0.f, 0.f);
        if (act) qv = *(const float2*)(qn + (size_t)n * OUTD + t * 2);
        Qs[t*2]   = qv.x;
        Qs[t*2+1] = qv.y;
        __syncthreads();

        // Sn[n][h] = b3_h . Q_h  (wave 0, 4 lanes per head)
        if (t < 64) {
            const int h = t >> 2, q = t & 3;
            float s = 0.f;
            #pragma unroll
            for (int d = 0; d < 8; ++d)
                s += b3s[h * HEAD_DIM + q * 8 + d] * Qs[h * HEAD_DIM + q * 8 + d];
            s += __shfl_xor(s, 1);
            s += __shfl_xor(s, 2);
            if (q == 0 && act) Sn[(size_t)n * HEADS + h] = s;
        }

        float accv[4];
        #pragma unroll
        for (int k = 0; k < 4; ++k) {
            const float4* qsrc = (const float4*)(Qs + (hb4 + k) * HEAD_DIM);
            float acc = 0.f;
            #pragma unroll
            for (int d4 = 0; d4 < 8; ++d4) {
                float4 v = qsrc[d4];
                acc += w3reg[k][d4*4+0] * v.x + w3reg[k][d4*4+1] * v.y
                     + w3reg[k][d4*4+2] * v.z + w3reg[k][d4*4+3] * v.w;
            }
            accv[k] = acc;
        }
        if (act)
            storeP4(Pn + (size_t)n * (HID * HEADS) + i * HEADS + hb4,
                    make_float4(accv[0], accv[1], accv[2], accv[3]));
        __syncthreads();   // protect Qs before next stage
    }
}

// -------- CSR build ----------------------------------------------------------
__global__ __launch_bounds__(256) void zero_counts_kernel(int* __restrict__ counts) {
    int t = blockIdx.x * 256 + threadIdx.x;
    if (t < N_NODES) counts[t] = 0;
}
__global__ __launch_bounds__(256) void hist_kernel(const int* __restrict__ center,
                                                   int* __restrict__ counts) {
    int e = blockIdx.x * 256 + threadIdx.x;
    if (e < N_EDGES) atomicAdd(&counts[center[e]], 1);
}
__global__ __launch_bounds__(SCAN_B) void scan1_kernel(
    const int* __restrict__ counts, int* __restrict__ incl, int* __restrict__ blockSums) {
    __shared__ int sm[SCAN_B];
    const int gid = blockIdx.x * SCAN_B + threadIdx.x;
    sm[threadIdx.x] = (gid < N_NODES) ? counts[gid] : 0;
    __syncthreads();
    #pragma unroll 1
    for (int off = 1; off < SCAN_B; off <<= 1) {
        int t = (threadIdx.x >= off) ? sm[threadIdx.x - off] : 0;
        __syncthreads();
        sm[threadIdx.x] += t;
        __syncthreads();
    }
    if (gid < N_NODES) incl[gid] = sm[threadIdx.x];
    if (threadIdx.x == SCAN_B - 1) blockSums[blockIdx.x] = sm[threadIdx.x];
}
__global__ void scan2_kernel(int* __restrict__ blockSums) {
    if (threadIdx.x == 0 && blockIdx.x == 0) {
        int run = 0;
        for (int i = 0; i < NSB; ++i) { int t = blockSums[i]; blockSums[i] = run; run += t; }
    }
}
__global__ __launch_bounds__(SCAN_B) void scan3_kernel(
    const int* __restrict__ counts, const int* __restrict__ incl,
    const int* __restrict__ blockSums, int* __restrict__ rowStart,
    int* __restrict__ cursor) {
    const int gid = blockIdx.x * SCAN_B + threadIdx.x;
    if (gid < N_NODES) {
        const int excl = incl[gid] - counts[gid] + blockSums[blockIdx.x];
        rowStart[gid] = excl;
        cursor[gid]   = excl;
    }
    if (gid == 0) rowStart[N_NODES] = N_EDGES;
}
__global__ __launch_bounds__(256) void fill_kernel(const int* __restrict__ center,
                                                   int* __restrict__ cursor,
                                                   int* __restrict__ edgeList,
                                                   int* __restrict__ nodeOf) {
    int e = blockIdx.x * 256 + threadIdx.x;
    if (e < N_EDGES) {
        const int c = center[e];
        int pos = atomicAdd(&cursor[c], 1);
        edgeList[pos] = e;
        nodeOf[pos]   = c;
    }
}

// -------- W-pass (CSR slot order): K-MLP 1-2 + W = (h2.P + s)*isqrtd ---------
template <typename PT>
__global__ __launch_bounds__(256) void wpass2_kernel(
    const int* __restrict__ edgeList, const int* __restrict__ nodeOf,
    const float* __restrict__ edge_feat,
    const float* __restrict__ w1T, const float* __restrict__ b1,
    const float* __restrict__ w2T, const float* __restrict__ b2,
    const PT* __restrict__ Pn, const float* __restrict__ Sn,
    float* __restrict__ Wbuf) {
    const int p = blockIdx.x * 256 + threadIdx.x;
    if (p >= N_EDGES) return;
    const int e = edgeList[p];
    const int c = nodeOf[p];

    float x[NES];
    const float4* ef4 = reinterpret_cast<const float4*>(edge_feat + (size_t)e * EDGE_DIM);
    #pragma unroll
    for (int i = 0; i < NES / 4; ++i) {
        float4 t = ef4[i];
        x[4*i+0] = t.x; x[4*i+1] = t.y; x[4*i+2] = t.z; x[4*i+3] = t.w;
    }

    float h1[HID];
    #pragma unroll
    for (int j = 0; j < HID; ++j) {
        float a = b1[j];
        #pragma unroll
        for (int i = 0; i < NES; ++i) a += x[i] * w1T[j * NES + i];
        h1[j] = silu_f(a);
    }

    float wacc[HEADS];
    {
        const float4* s4 = (const float4*)(Sn + (size_t)c * HEADS);
        #pragma unroll
        for (int k = 0; k < 4; ++k) {
            float4 v = s4[k];
            wacc[4*k+0] = v.x; wacc[4*k+1] = v.y; wacc[4*k+2] = v.z; wacc[4*k+3] = v.w;
        }
    }

    const PT* prow = Pn + (size_t)c * (HID * HEADS);
    #pragma unroll 2
    for (int j = 0; j < HID; ++j) {
        float a = b2[j];
        #pragma unroll
        for (int i = 0; i < HID; ++i) a += h1[i] * w2T[j * HID + i];
        const float h2 = silu_f(a);
        float pv[HEADS];
        loadP16(prow + j * HEADS, pv);
        #pragma unroll
        for (int hh = 0; hh < HEADS; ++hh) wacc[hh] += h2 * pv[hh];
    }

    float4* wrow = (float4*)(Wbuf + (size_t)p * HEADS);
    #pragma unroll
    for (int k = 0; k < 4; ++k) {
        wrow[k] = make_float4(wacc[4*k+0] * ISQRTD, wacc[4*k+1] * ISQRTD,
                              wacc[4*k+2] * ISQRTD, wacc[4*k+3] * ISQRTD);
    }
}

// -------- node gather: softmax + weighted sum, atomic-free -------------------
__global__ __launch_bounds__(256) void gather2_kernel(
    const int* __restrict__ rowStart, const int* __restrict__ edgeList,
    const float* __restrict__ edge_feat, const float* __restrict__ Wbuf,
    float* __restrict__ out) {
    const int wid  = threadIdx.x >> 6;
    const int lane = threadIdx.x & 63;
    const int n = blockIdx.x * 4 + wid;
    if (n >= N_NODES) return;
    const int rs = rowStart[n];
    const int d  = rowStart[n + 1] - rs;

    const int c0 = lane, c1 = lane + 64, c2 = lane + 128;
    const int h0 = headOf(c0);
    const int h1 = headOf(c1);
    const int h2 = (c2 < EDGE_DIM) ? headOf(c2) : 0;

    float acc0 = 0.f, acc1 = 0.f, acc2 = 0.f;
    if (d > 0) {
        const int hh  = lane & 15;
        const int sub = lane >> 4;
        float m = -3.0e38f;
        for (int i = sub; i < d; i += 4)
            m = fmaxf(m, Wbuf[(size_t)(rs + i) * HEADS + hh]);
        m = fmaxf(m, __shfl_xor(m, 16));
        m = fmaxf(m, __shfl_xor(m, 32));
        float s = 0.f;
        for (int i = sub; i < d; i += 4)
            s += __expf(Wbuf[(size_t)(rs + i) * HEADS + hh] - m);
        s += __shfl_xor(s, 16);
        s += __shfl_xor(s, 32);
        const float rden = 1.0f / s;

        for (int i = 0; i < d; ++i) {
            const int e = edgeList[rs + i];
            const float aL = __expf(Wbuf[(size_t)(rs + i) * HEADS + hh] - m) * rden;
            const float a0 = __shfl(aL, h0);
            const float a1 = __shfl(aL, h1);
            const float a2 = __shfl(aL, h2);
            const float* fr = edge_feat + (size_t)e * EDGE_DIM;
            acc0 += fr[c0] * a0;
            acc1 += fr[c1] * a1;
            if (c2 < EDGE_DIM) acc2 += fr[c2] * a2;
        }
    }
    float* orow = out + (size_t)n * EDGE_DIM;
    orow[c0] = acc0;
    orow[c1] = acc1;
    if (c2 < EDGE_DIM) orow[c2] = acc2;
}

// ==================== fallback-only kernels (small workspace) ================
template <typename QT>
__global__ __launch_bounds__(256) void qmlp_kernel(
    const float* __restrict__ node_attrs,
    const float* __restrict__ w1, const float* __restrict__ b1,
    const float* __restrict__ w2, const float* __restrict__ b2,
    const float* __restrict__ w3, const float* __restrict__ b3,
    QT* __restrict__ qn) {
    __shared__ float xs[4][NNS];
    __shared__ float hs[4][HID];
    const int wid  = threadIdx.x >> 6;
    const int lane = threadIdx.x & 63;
    const int node = blockIdx.x * 4 + wid;
    const bool act = node < N_NODES;

    xs[wid][lane] = act ? node_attrs[(size_t)node * NNS + lane] : 0.0f;
    __syncthreads();
    float a = b1[lane];
    #pragma unroll
    for (int i = 0; i < NNS; ++i) a += xs[wid][i] * w1[i * HID + lane];
    a = silu_f(a);
    hs[wid][lane] = a;
    __syncthreads();
    float a2 = b2[lane];
    #pragma unroll
    for (int i = 0; i < HID; ++i) a2 += hs[wid][i] * w2[i * HID + lane];
    a2 = silu_f(a2);
    __syncthreads();
    xs[wid][lane] = a2;
    __syncthreads();
    if (act) {
        #pragma unroll 1
        for (int j8 = 0; j8 < 8; ++j8) {
            const int col = j8 * 64 + lane;
            float acc = b3[col];
            #pragma unroll
            for (int i = 0; i < HID; ++i) acc += xs[wid][i] * w3[i * OUTD + col];
            storeQ(qn + (size_t)node * OUTD + col, acc);
        }
    }
}

__global__ __launch_bounds__(256) void init_kernel(float* __restrict__ out,
                                                   float* __restrict__ denom,
                                                   unsigned* __restrict__ segmax) {
    int t = blockIdx.x * 256 + threadIdx.x;
    if (t < N_NODES * EDGE_DIM) out[t] = 0.0f;
    if (t < N_NODES * HEADS) {
        denom[t]  = 0.0f;
        segmax[t] = 0u;
    }
}

template <typename QT>
__global__ __launch_bounds__(256) void kmlp_kernel(
    const int* __restrict__ center, const float* __restrict__ edge_feat,
    const float* __restrict__ w1, const float* __restrict__ b1,
    const float* __restrict__ w2, const float* __restrict__ b2,
    const float* __restrict__ w3, const float* __restrict__ b3,
    const QT* __restrict__ qn, float* __restrict__ Wbuf,
    unsigned* __restrict__ segmax) {
    const int e = blockIdx.x * 256 + threadIdx.x;
    if (e >= N_EDGES) return;
    const int c = center[e];
    float x[NES];
    const float4* ef4 = reinterpret_cast<const float4*>(edge_feat + (size_t)e * EDGE_DIM);
    #pragma unroll
    for (int i = 0; i < NES / 4; ++i) {
        float4 t = ef4[i];
        x[4*i+0] = t.x; x[4*i+1] = t.y; x[4*i+2] = t.z; x[4*i+3] = t.w;
    }
    float h1[HID];
    #pragma unroll
    for (int j = 0; j < HID; ++j) {
        float a = 0.f;
        #pragma unroll
        for (int i = 0; i < NES; ++i) a += x[i] * w1[i * HID + j];
        h1[j] = silu_f(b1[j] + a);
    }
    float h2[HID];
    #pragma unroll
    for (int j = 0; j < HID; ++j) {
        float a = 0.f;
        #pragma unroll
        for (int i = 0; i < HID; ++i) a += h1[i] * w2[i * HID + j];
        h2[j] = silu_f(b2[j] + a);
    }
    const QT* q = qn + (size_t)c * OUTD;
    #pragma unroll 1
    for (int h = 0; h < HEADS; ++h) {
        float wacc = 0.0f;
        #pragma unroll 1
        for (int jj = 0; jj < HEAD_DIM; ++jj) {
            const int j = h * HEAD_DIM + jj;
            float a = 0.f;
            #pragma unroll
            for (int i = 0; i < HID; ++i) a += h2[i] * w3[i * OUTD + j];
            wacc += (b3[j] + a) * loadQ(q + j);
        }
        const float Wv = wacc * ISQRTD;
        Wbuf[(size_t)e * HEADS + h] = Wv;
        atomicMax(&segmax[c * HEADS + h], fenc(Wv));
    }
}

__global__ __launch_bounds__(256) void ex_denom_kernel(
    const int* __restrict__ center, const unsigned* __restrict__ segmax,
    float* __restrict__ Wbuf, float* __restrict__ denom) {
    const int t = blockIdx.x * 256 + threadIdx.x;
    if (t >= N_EDGES * HEADS) return;
    const int e = t >> 4;
    const int h = t & 15;
    const int c = center[e];
    const float m  = fdec(segmax[c * HEADS + h]);
    const float ex = __expf(Wbuf[t] - m);
    Wbuf[t] = ex;
    atomicAdd(&denom[c * HEADS + h], ex);
}

__global__ __launch_bounds__(256) void attn_kernel(
    const int* __restrict__ center, float* __restrict__ Wbuf,
    const float* __restrict__ denom) {
    const int t = blockIdx.x * 256 + threadIdx.x;
    if (t >= N_EDGES * HEADS) return;
    const int e = t >> 4;
    const int h = t & 15;
    Wbuf[t] = Wbuf[t] / denom[center[e] * HEADS + h];
}

__global__ __launch_bounds__(256) void scatter4_kernel(
    const int* __restrict__ center, const float* __restrict__ edge_feat,
    const float* __restrict__ attn, float* __restrict__ out) {
    const int t = blockIdx.x * 256 + threadIdx.x;
    if (t >= N_EDGES * (EDGE_DIM / 4)) return;
    const int e  = t / (EDGE_DIM / 4);
    const int cg = t - e * (EDGE_DIM / 4);
    const int c  = center[e];
    const float4 f = *(const float4*)(edge_feat + (size_t)e * EDGE_DIM + cg * 4);
    const float* arow = attn + (size_t)e * HEADS;
    const float vals[4] = {f.x, f.y, f.z, f.w};
    #pragma unroll
    for (int k = 0; k < 4; ++k) {
        const int col = cg * 4 + k;
        const int h = headOf(col);
        atomicAdd(out + (size_t)c * EDGE_DIM + col, vals[k] * arow[h]);
    }
}

extern "C" void kernel_launch(void* const* d_in, const int* in_sizes, int n_in,
                              void* d_out, int out_size, void* d_ws, size_t ws_size,
                              hipStream_t stream) {
    const int*   edge_index = (const int*)d_in[0];
    const float* edge_feat  = (const float*)d_in[1];
    const float* node_attrs = (const float*)d_in[2];
    const float* q_w1 = (const float*)d_in[3];
    const float* q_b1 = (const float*)d_in[4];
    const float* q_w2 = (const float*)d_in[5];
    const float* q_b2 = (const float*)d_in[6];
    const float* q_w3 = (const float*)d_in[7];
    const float* q_b3 = (const float*)d_in[8];
    const float* k_w1 = (const float*)d_in[9];
    const float* k_b1 = (const float*)d_in[10];
    const float* k_w2 = (const float*)d_in[11];
    const float* k_b2 = (const float*)d_in[12];
    const float* k_w3 = (const float*)d_in[13];
    const float* k_b3 = (const float*)d_in[14];
    const int* center = edge_index;
    float* out = (float*)d_out;

    const size_t szQ    = (size_t)N_NODES * OUTD * sizeof(float);          // 102.4 MB
    const size_t szPf   = (size_t)N_NODES * HID * HEADS * sizeof(float);   // 204.8 MB
    const size_t szPb   = szPf / 2;
    const size_t szS    = (size_t)N_NODES * HEADS * sizeof(float);         //   3.2 MB
    const size_t szW    = (size_t)N_EDGES * HEADS * sizeof(float);         //  25.6 MB
    const size_t szDen  = (size_t)N_NODES * HEADS * sizeof(float);
    const size_t szT    = (NES * HID + HID * HID) * sizeof(float);

    const int qmlp2Grid   = (N_NODES + NPB_Q - 1) / NPB_Q;   // 3125
    const int pGrid2      = (N_NODES + NPB_P - 1) / NPB_P;   // 2000
    const int edgeGrid    = (N_EDGES + 255) / 256;
    const int nodeGrid256 = (N_NODES + 255) / 256;
    const int gatherGrid  = (N_NODES + 3) / 4;
    const int ehGrid      = (N_EDGES * HEADS + 255) / 256;

    const bool pathF32  = ws_size >= szQ + szPf + szS + szT;
    const bool pathBf16 = ws_size >= szQ + szPb + szS + szT;

    if (pathF32 || pathBf16) {
        // Layout: [Qn | Pn | Sn | w1T | w2T]. After pcompute2, Qn region is
        // reused for [Wbuf | counts | incl | rowStart | cursor | blockSums | edgeList | nodeOf].
        char* base = (char*)d_ws;
        float* Qn = (float*)base;
        char* pP  = base + szQ;
        const size_t szP = pathF32 ? szPf : szPb;
        char* pS  = pP + szP;
        float* Sn  = (float*)pS;
        float* w1T = (float*)(pS + szS);
        float* w2T = w1T + NES * HID;

        float* Wbuf     = (float*)base;                      // aliases Qn (dead)
        int*   counts   = (int*)(base + szW);
        int*   incl     = counts + N_NODES;
        int*   rowStart = incl + N_NODES;                    // N_NODES+1
        int*   cursor   = rowStart + N_NODES + 1;
        int*   blockSums= cursor + N_NODES;
        int*   edgeList = blockSums + ((NSB + 63) & ~63);
        int*   nodeOf   = edgeList + N_EDGES;

        prep_kernel<<<16, 256, 0, stream>>>(k_w1, k_w2, w1T, w2T);
        qmlp2_kernel<<<qmlp2Grid, 256, 0, stream>>>(
            node_attrs, q_w1, q_b1, q_w2, q_b2, q_w3, q_b3, Qn);

        if (pathF32) {
            float* Pn = (float*)pP;
            pcompute2_kernel<float><<<pGrid2, 256, 0, stream>>>(Qn, k_w3, k_b3, Pn, Sn);
        } else {
            __hip_bfloat16* Pn = (__hip_bfloat16*)pP;
            pcompute2_kernel<__hip_bfloat16><<<pGrid2, 256, 0, stream>>>(Qn, k_w3, k_b3, Pn, Sn);
        }

        zero_counts_kernel<<<nodeGrid256, 256, 0, stream>>>(counts);
        hist_kernel<<<edgeGrid, 256, 0, stream>>>(center, counts);
        scan1_kernel<<<NSB, SCAN_B, 0, stream>>>(counts, incl, blockSums);
        scan2_kernel<<<1, 64, 0, stream>>>(blockSums);
        scan3_kernel<<<NSB, SCAN_B, 0, stream>>>(counts, incl, blockSums, rowStart, cursor);
        fill_kernel<<<edgeGrid, 256, 0, stream>>>(center, cursor, edgeList, nodeOf);

        if (pathF32) {
            float* Pn = (float*)pP;
            wpass2_kernel<float><<<edgeGrid, 256, 0, stream>>>(
                edgeList, nodeOf, edge_feat, w1T, k_b1, w2T, k_b2, Pn, Sn, Wbuf);
        } else {
            __hip_bfloat16* Pn = (__hip_bfloat16*)pP;
            wpass2_kernel<__hip_bfloat16><<<edgeGrid, 256, 0, stream>>>(
                edgeList, nodeOf, edge_feat, w1T, k_b1, w2T, k_b2, Pn, Sn, Wbuf);
        }

        gather2_kernel<<<gatherGrid, 256, 0, stream>>>(rowStart, edgeList, edge_feat, Wbuf, out);
        return;
    }

    // ---------------- fallback: atomic pipeline (small ws) -------------------
    char* p = (char*)d_ws;
    float*    Wbuf   = (float*)p;    p += szW;
    float*    denom  = (float*)p;    p += szDen;
    unsigned* segmax = (unsigned*)p; p += szDen;
    const size_t fbase = (size_t)(p - (char*)d_ws);
    const bool qf32 = ws_size >= fbase + szQ;

    const int initGrid    = (N_NODES * EDGE_DIM + 255) / 256;
    const int scatterGrid = (N_EDGES * (EDGE_DIM / 4) + 255) / 256;
    const int qmlpGrid    = (N_NODES + 3) / 4;

    init_kernel<<<initGrid, 256, 0, stream>>>(out, denom, segmax);
    if (qf32) {
        float* qn = (float*)p;
        qmlp_kernel<float><<<qmlpGrid, 256, 0, stream>>>(
            node_attrs, q_w1, q_b1, q_w2, q_b2, q_w3, q_b3, qn);
        kmlp_kernel<float><<<edgeGrid, 256, 0, stream>>>(
            center, edge_feat, k_w1, k_b1, k_w2, k_b2, k_w3, k_b3, qn, Wbuf, segmax);
    } else {
        __hip_bfloat16* qn = (__hip_bfloat16*)p;
        qmlp_kernel<__hip_bfloat16><<<qmlpGrid, 256, 0, stream>>>(
            node_attrs, q_w1, q_b1, q_w2, q_b2, q_w3, q_b3, qn);
        kmlp_kernel<__hip_bfloat16><<<edgeGrid, 256, 0, stream>>>(
            center, edge_feat, k_w1, k_b1, k_w2, k_b2, k_w3, k_b3, qn, Wbuf, segmax);
    }
    ex_denom_kernel<<<ehGrid, 256, 0, stream>>>(center, segmax, Wbuf, denom);
    attn_kernel<<<ehGrid, 256, 0, stream>>>(center, Wbuf, denom);
    scatter4_kernel<<<scatterGrid, 256, 0, stream>>>(center, edge_feat, Wbuf, out);
}

// Round 6
// 692.557 us; speedup vs baseline: 3.9699x; 1.1412x over previous
//
#include <hip/hip_runtime.h>
#include <hip/hip_bf16.h>

constexpr int N_NODES  = 50000;
constexpr int N_EDGES  = 400000;
constexpr int EDGE_DIM = 144;
constexpr int HEADS    = 16;
constexpr int HEAD_DIM = 32;
constexpr int OUTD     = 512;   // HEADS*HEAD_DIM
constexpr int HID      = 64;
constexpr int NES      = 16;
constexpr int NNS      = 64;
constexpr int SCAN_B   = 512;
constexpr int NSB      = (N_NODES + SCAN_B - 1) / SCAN_B;   // 98
constexpr int NPB_P    = 25;    // nodes per block, pcompute3 (50000 = 2000*25)
constexpr int NPB_Q    = 16;    // nodes per block, qmlp2    (50000 = 3125*16)
constexpr int QPAD     = 36;    // padded head stride in LDS (floats): bank=(4h+d)%32 -> 2-way max
#define ISQRTD 0.17677669529663687f

__device__ __forceinline__ float silu_f(float x) {
    return x / (1.0f + __expf(-x));
}

__device__ __forceinline__ unsigned fenc(float f) {
    unsigned u = __float_as_uint(f);
    return (u & 0x80000000u) ? ~u : (u | 0x80000000u);
}
__device__ __forceinline__ float fdec(unsigned m) {
    unsigned u = (m & 0x80000000u) ? (m ^ 0x80000000u) : ~m;
    return __uint_as_float(u);
}

__device__ __forceinline__ int headOf(int col) {
    return (col < 16) ? col : ((col < 64) ? (col - 16) / 3 : (col - 64) / 5);
}

__device__ __forceinline__ void storeQ(float* p, float v) { *p = v; }
__device__ __forceinline__ void storeQ(__hip_bfloat16* p, float v) { *p = __float2bfloat16(v); }
__device__ __forceinline__ float loadQ(const float* p) { return *p; }
__device__ __forceinline__ float loadQ(const __hip_bfloat16* p) { return __bfloat162float(*p); }

__device__ __forceinline__ void loadP16(const float* p, float* o) {
    const float4* p4 = (const float4*)p;
    #pragma unroll
    for (int k = 0; k < 4; ++k) {
        float4 v = p4[k];
        o[4*k+0] = v.x; o[4*k+1] = v.y; o[4*k+2] = v.z; o[4*k+3] = v.w;
    }
}
__device__ __forceinline__ void loadP16(const __hip_bfloat16* p, float* o) {
    const uint4* p4 = (const uint4*)p;
    #pragma unroll
    for (int k = 0; k < 2; ++k) {
        uint4 v = p4[k];
        o[8*k+0] = __uint_as_float(v.x << 16);
        o[8*k+1] = __uint_as_float(v.x & 0xffff0000u);
        o[8*k+2] = __uint_as_float(v.y << 16);
        o[8*k+3] = __uint_as_float(v.y & 0xffff0000u);
        o[8*k+4] = __uint_as_float(v.z << 16);
        o[8*k+5] = __uint_as_float(v.z & 0xffff0000u);
        o[8*k+6] = __uint_as_float(v.w << 16);
        o[8*k+7] = __uint_as_float(v.w & 0xffff0000u);
    }
}

// -------- prep: transpose k_w1 (16x64 -> 64x16) and k_w2 (64x64) -------------
__global__ __launch_bounds__(256) void prep_kernel(
    const float* __restrict__ w1, const float* __restrict__ w2,
    float* __restrict__ w1T, float* __restrict__ w2T) {
    int t = blockIdx.x * 256 + threadIdx.x;
    if (t < NES * HID) {
        int i = t / HID, j = t % HID;
        w1T[j * NES + i] = w1[t];
    }
    if (t < HID * HID) {
        int i = t / HID, j = t % HID;
        w2T[j * HID + i] = w2[t];
    }
}

// -------- Q-MLP v2: layers 1-2 wave-per-node, layer 3 via persistent regs ----
__global__ __launch_bounds__(256) void qmlp2_kernel(
    const float* __restrict__ node_attrs,
    const float* __restrict__ w1, const float* __restrict__ b1,
    const float* __restrict__ w2, const float* __restrict__ b2,
    const float* __restrict__ w3, const float* __restrict__ b3,
    float* __restrict__ qn) {
    const int t    = threadIdx.x;
    const int wid  = t >> 6;
    const int lane = t & 63;
    const int n0   = blockIdx.x * NPB_Q;

    // persistent layer-3 weights: this thread owns cols t and t+256
    float w3a[HID], w3b[HID];
    #pragma unroll
    for (int i = 0; i < HID; ++i) {
        w3a[i] = w3[(size_t)i * OUTD + t];
        w3b[i] = w3[(size_t)i * OUTD + 256 + t];
    }

    __shared__ float xs[4][NNS];
    __shared__ float h1s[4][HID];
    __shared__ float h2s[NPB_Q][HID];

    #pragma unroll 1
    for (int r = 0; r < NPB_Q / 4; ++r) {
        const int n   = n0 + r * 4 + wid;
        const bool act = n < N_NODES;
        xs[wid][lane] = act ? node_attrs[(size_t)n * NNS + lane] : 0.0f;
        __syncthreads();
        float a = b1[lane];
        #pragma unroll
        for (int i = 0; i < NNS; ++i) a += xs[wid][i] * w1[i * HID + lane];
        h1s[wid][lane] = silu_f(a);
        __syncthreads();
        float a2 = b2[lane];
        #pragma unroll
        for (int i = 0; i < HID; ++i) a2 += h1s[wid][i] * w2[i * HID + lane];
        h2s[r * 4 + wid][lane] = silu_f(a2);
        __syncthreads();
    }

    #pragma unroll 1
    for (int m = 0; m < NPB_Q; ++m) {
        const int n = n0 + m;
        if (n >= N_NODES) break;
        float acc0 = b3[t], acc1 = b3[256 + t];
        #pragma unroll
        for (int i = 0; i < HID; ++i) {
            const float h = h2s[m][i];
            acc0 += h * w3a[i];
            acc1 += h * w3b[i];
        }
        qn[(size_t)n * OUTD + t]       = acc0;
        qn[(size_t)n * OUTD + 256 + t] = acc1;
    }
}

// -------- pcompute v3: thread = (4 rows, 1 head); padded LDS Q ---------------
// LDS reads per thread per node: 32 floats (vs 128 in v2); bank conflicts <=2-way.
template <typename PT>
__global__ __launch_bounds__(256) void pcompute3_kernel(
    const float* __restrict__ qn, const float* __restrict__ w3,
    const float* __restrict__ b3,
    PT* __restrict__ Pn, float* __restrict__ Sn) {
    const int t  = threadIdx.x;
    const int h  = t & 15;          // head owned by this thread
    const int rg = t >> 4;          // row group: rows rg*4 .. rg*4+3

    // persistent weights: w3reg[j][d] = w3[rg*4+j][h*32+d]
    float w3reg[4][HEAD_DIM];
    #pragma unroll
    for (int j = 0; j < 4; ++j) {
        const float4* src = (const float4*)(w3 + (size_t)(rg * 4 + j) * OUTD + h * HEAD_DIM);
        #pragma unroll
        for (int d4 = 0; d4 < 8; ++d4) {
            float4 v = src[d4];
            w3reg[j][d4*4+0] = v.x; w3reg[j][d4*4+1] = v.y;
            w3reg[j][d4*4+2] = v.z; w3reg[j][d4*4+3] = v.w;
        }
    }

    __shared__ float Qs[HEADS * QPAD];   // head hh at Qs + hh*QPAD (padded)
    __shared__ float b3s[OUTD];
    b3s[t]       = b3[t];
    b3s[t + 256] = b3[t + 256];

    const int n0 = blockIdx.x * NPB_P;
    #pragma unroll 1
    for (int m = 0; m < NPB_P; ++m) {
        const int n = n0 + m;
        const bool act = n < N_NODES;
        float2 qv = make_float2(0.f, 0.f);
        if (act) qv = *(const float2*)(qn + (size_t)n * OUTD + t * 2);
        __syncthreads();   // previous iteration's Qs readers done
        {
            const int hh = t >> 4;          // (2t)/32
            const int dd = (2 * t) & 31;
            *(float2*)(Qs + hh * QPAD + dd) = qv;
        }
        __syncthreads();

        // Sn[n][hh] = b3_hh . Q_hh  (wave 0, 4 lanes per head)
        if (t < 64) {
            const int hh = t >> 2, q = t & 3;
            float s = 0.f;
            #pragma unroll
            for (int d = 0; d < 8; ++d)
                s += b3s[hh * HEAD_DIM + q * 8 + d] * Qs[hh * QPAD + q * 8 + d];
            s += __shfl_xor(s, 1);
            s += __shfl_xor(s, 2);
            if (q == 0 && act) Sn[(size_t)n * HEADS + hh] = s;
        }

        float acc0 = 0.f, acc1 = 0.f, acc2 = 0.f, acc3 = 0.f;
        const float4* qsrc = (const float4*)(Qs + h * QPAD);
        #pragma unroll
        for (int d4 = 0; d4 < 8; ++d4) {
            const float4 v = qsrc[d4];
            acc0 += w3reg[0][d4*4+0]*v.x + w3reg[0][d4*4+1]*v.y + w3reg[0][d4*4+2]*v.z + w3reg[0][d4*4+3]*v.w;
            acc1 += w3reg[1][d4*4+0]*v.x + w3reg[1][d4*4+1]*v.y + w3reg[1][d4*4+2]*v.z + w3reg[1][d4*4+3]*v.w;
            acc2 += w3reg[2][d4*4+0]*v.x + w3reg[2][d4*4+1]*v.y + w3reg[2][d4*4+2]*v.z + w3reg[2][d4*4+3]*v.w;
            acc3 += w3reg[3][d4*4+0]*v.x + w3reg[3][d4*4+1]*v.y + w3reg[3][d4*4+2]*v.z + w3reg[3][d4*4+3]*v.w;
        }
        if (act) {
            PT* prow = Pn + (size_t)n * (HID * HEADS) + (rg * 4) * HEADS + h;
            storeQ(prow,             acc0);
            storeQ(prow + HEADS,     acc1);
            storeQ(prow + 2 * HEADS, acc2);
            storeQ(prow + 3 * HEADS, acc3);
        }
    }
}

// -------- CSR build ----------------------------------------------------------
__global__ __launch_bounds__(256) void zero_counts_kernel(int* __restrict__ counts) {
    int t = blockIdx.x * 256 + threadIdx.x;
    if (t < N_NODES) counts[t] = 0;
}
__global__ __launch_bounds__(256) void hist_kernel(const int* __restrict__ center,
                                                   int* __restrict__ counts) {
    int e = blockIdx.x * 256 + threadIdx.x;
    if (e < N_EDGES) atomicAdd(&counts[center[e]], 1);
}
__global__ __launch_bounds__(SCAN_B) void scan1_kernel(
    const int* __restrict__ counts, int* __restrict__ incl, int* __restrict__ blockSums) {
    __shared__ int sm[SCAN_B];
    const int gid = blockIdx.x * SCAN_B + threadIdx.x;
    sm[threadIdx.x] = (gid < N_NODES) ? counts[gid] : 0;
    __syncthreads();
    #pragma unroll 1
    for (int off = 1; off < SCAN_B; off <<= 1) {
        int t = (threadIdx.x >= off) ? sm[threadIdx.x - off] : 0;
        __syncthreads();
        sm[threadIdx.x] += t;
        __syncthreads();
    }
    if (gid < N_NODES) incl[gid] = sm[threadIdx.x];
    if (threadIdx.x == SCAN_B - 1) blockSums[blockIdx.x] = sm[threadIdx.x];
}
__global__ void scan2_kernel(int* __restrict__ blockSums) {
    if (threadIdx.x == 0 && blockIdx.x == 0) {
        int run = 0;
        for (int i = 0; i < NSB; ++i) { int t = blockSums[i]; blockSums[i] = run; run += t; }
    }
}
__global__ __launch_bounds__(SCAN_B) void scan3_kernel(
    const int* __restrict__ counts, const int* __restrict__ incl,
    const int* __restrict__ blockSums, int* __restrict__ rowStart,
    int* __restrict__ cursor) {
    const int gid = blockIdx.x * SCAN_B + threadIdx.x;
    if (gid < N_NODES) {
        const int excl = incl[gid] - counts[gid] + blockSums[blockIdx.x];
        rowStart[gid] = excl;
        cursor[gid]   = excl;
    }
    if (gid == 0) rowStart[N_NODES] = N_EDGES;
}
__global__ __launch_bounds__(256) void fill_kernel(const int* __restrict__ center,
                                                   int* __restrict__ cursor,
                                                   int* __restrict__ edgeList,
                                                   int* __restrict__ nodeOf) {
    int e = blockIdx.x * 256 + threadIdx.x;
    if (e < N_EDGES) {
        const int c = center[e];
        int pos = atomicAdd(&cursor[c], 1);
        edgeList[pos] = e;
        nodeOf[pos]   = c;
    }
}

// -------- W-pass (CSR slot order): K-MLP 1-2 + W = (h2.P + s)*isqrtd ---------
template <typename PT>
__global__ __launch_bounds__(256) void wpass2_kernel(
    const int* __restrict__ edgeList, const int* __restrict__ nodeOf,
    const float* __restrict__ edge_feat,
    const float* __restrict__ w1T, const float* __restrict__ b1,
    const float* __restrict__ w2T, const float* __restrict__ b2,
    const PT* __restrict__ Pn, const float* __restrict__ Sn,
    float* __restrict__ Wbuf) {
    const int p = blockIdx.x * 256 + threadIdx.x;
    if (p >= N_EDGES) return;
    const int e = edgeList[p];
    const int c = nodeOf[p];

    float x[NES];
    const float4* ef4 = reinterpret_cast<const float4*>(edge_feat + (size_t)e * EDGE_DIM);
    #pragma unroll
    for (int i = 0; i < NES / 4; ++i) {
        float4 t = ef4[i];
        x[4*i+0] = t.x; x[4*i+1] = t.y; x[4*i+2] = t.z; x[4*i+3] = t.w;
    }

    float h1[HID];
    #pragma unroll
    for (int j = 0; j < HID; ++j) {
        float a = b1[j];
        #pragma unroll
        for (int i = 0; i < NES; ++i) a += x[i] * w1T[j * NES + i];
        h1[j] = silu_f(a);
    }

    float wacc[HEADS];
    {
        const float4* s4 = (const float4*)(Sn + (size_t)c * HEADS);
        #pragma unroll
        for (int k = 0; k < 4; ++k) {
            float4 v = s4[k];
            wacc[4*k+0] = v.x; wacc[4*k+1] = v.y; wacc[4*k+2] = v.z; wacc[4*k+3] = v.w;
        }
    }

    const PT* prow = Pn + (size_t)c * (HID * HEADS);
    #pragma unroll 2
    for (int j = 0; j < HID; ++j) {
        float a = b2[j];
        #pragma unroll
        for (int i = 0; i < HID; ++i) a += h1[i] * w2T[j * HID + i];
        const float h2 = silu_f(a);
        float pv[HEADS];
        loadP16(prow + j * HEADS, pv);
        #pragma unroll
        for (int hh = 0; hh < HEADS; ++hh) wacc[hh] += h2 * pv[hh];
    }

    float4* wrow = (float4*)(Wbuf + (size_t)p * HEADS);
    #pragma unroll
    for (int k = 0; k < 4; ++k) {
        wrow[k] = make_float4(wacc[4*k+0] * ISQRTD, wacc[4*k+1] * ISQRTD,
                              wacc[4*k+2] * ISQRTD, wacc[4*k+3] * ISQRTD);
    }
}

// -------- node gather: softmax + weighted sum, atomic-free -------------------
__global__ __launch_bounds__(256) void gather2_kernel(
    const int* __restrict__ rowStart, const int* __restrict__ edgeList,
    const float* __restrict__ edge_feat, const float* __restrict__ Wbuf,
    float* __restrict__ out) {
    const int wid  = threadIdx.x >> 6;
    const int lane = threadIdx.x & 63;
    const int n = blockIdx.x * 4 + wid;
    if (n >= N_NODES) return;
    const int rs = rowStart[n];
    const int d  = rowStart[n + 1] - rs;

    const int c0 = lane, c1 = lane + 64, c2 = lane + 128;
    const int h0 = headOf(c0);
    const int h1 = headOf(c1);
    const int h2 = (c2 < EDGE_DIM) ? headOf(c2) : 0;

    float acc0 = 0.f, acc1 = 0.f, acc2 = 0.f;
    if (d > 0) {
        const int hh  = lane & 15;
        const int sub = lane >> 4;
        float m = -3.0e38f;
        for (int i = sub; i < d; i += 4)
            m = fmaxf(m, Wbuf[(size_t)(rs + i) * HEADS + hh]);
        m = fmaxf(m, __shfl_xor(m, 16));
        m = fmaxf(m, __shfl_xor(m, 32));
        float s = 0.f;
        for (int i = sub; i < d; i += 4)
            s += __expf(Wbuf[(size_t)(rs + i) * HEADS + hh] - m);
        s += __shfl_xor(s, 16);
        s += __shfl_xor(s, 32);
        const float rden = 1.0f / s;

        for (int i = 0; i < d; ++i) {
            const int e = edgeList[rs + i];
            const float aL = __expf(Wbuf[(size_t)(rs + i) * HEADS + hh] - m) * rden;
            const float a0 = __shfl(aL, h0);
            const float a1 = __shfl(aL, h1);
            const float a2 = __shfl(aL, h2);
            const float* fr = edge_feat + (size_t)e * EDGE_DIM;
            acc0 += fr[c0] * a0;
            acc1 += fr[c1] * a1;
            if (c2 < EDGE_DIM) acc2 += fr[c2] * a2;
        }
    }
    float* orow = out + (size_t)n * EDGE_DIM;
    orow[c0] = acc0;
    orow[c1] = acc1;
    if (c2 < EDGE_DIM) orow[c2] = acc2;
}

// ==================== fallback-only kernels (small workspace) ================
template <typename QT>
__global__ __launch_bounds__(256) void qmlp_kernel(
    const float* __restrict__ node_attrs,
    const float* __restrict__ w1, const float* __restrict__ b1,
    const float* __restrict__ w2, const float* __restrict__ b2,
    const float* __restrict__ w3, const float* __restrict__ b3,
    QT* __restrict__ qn) {
    __shared__ float xs[4][NNS];
    __shared__ float hs[4][HID];
    const int wid  = threadIdx.x >> 6;
    const int lane = threadIdx.x & 63;
    const int node = blockIdx.x * 4 + wid;
    const bool act = node < N_NODES;

    xs[wid][lane] = act ? node_attrs[(size_t)node * NNS + lane] : 0.0f;
    __syncthreads();
    float a = b1[lane];
    #pragma unroll
    for (int i = 0; i < NNS; ++i) a += xs[wid][i] * w1[i * HID + lane];
    a = silu_f(a);
    hs[wid][lane] = a;
    __syncthreads();
    float a2 = b2[lane];
    #pragma unroll
    for (int i = 0; i < HID; ++i) a2 += hs[wid][i] * w2[i * HID + lane];
    a2 = silu_f(a2);
    __syncthreads();
    xs[wid][lane] = a2;
    __syncthreads();
    if (act) {
        #pragma unroll 1
        for (int j8 = 0; j8 < 8; ++j8) {
            const int col = j8 * 64 + lane;
            float acc = b3[col];
            #pragma unroll
            for (int i = 0; i < HID; ++i) acc += xs[wid][i] * w3[i * OUTD + col];
            storeQ(qn + (size_t)node * OUTD + col, acc);
        }
    }
}

__global__ __launch_bounds__(256) void init_kernel(float* __restrict__ out,
                                                   float* __restrict__ denom,
                                                   unsigned* __restrict__ segmax) {
    int t = blockIdx.x * 256 + threadIdx.x;
    if (t < N_NODES * EDGE_DIM) out[t] = 0.0f;
    if (t < N_NODES * HEADS) {
        denom[t]  = 0.0f;
        segmax[t] = 0u;
    }
}

template <typename QT>
__global__ __launch_bounds__(256) void kmlp_kernel(
    const int* __restrict__ center, const float* __restrict__ edge_feat,
    const float* __restrict__ w1, const float* __restrict__ b1,
    const float* __restrict__ w2, const float* __restrict__ b2,
    const float* __restrict__ w3, const float* __restrict__ b3,
    const QT* __restrict__ qn, float* __restrict__ Wbuf,
    unsigned* __restrict__ segmax) {
    const int e = blockIdx.x * 256 + threadIdx.x;
    if (e >= N_EDGES) return;
    const int c = center[e];
    float x[NES];
    const float4* ef4 = reinterpret_cast<const float4*>(edge_feat + (size_t)e * EDGE_DIM);
    #pragma unroll
    for (int i = 0; i < NES / 4; ++i) {
        float4 t = ef4[i];
        x[4*i+0] = t.x; x[4*i+1] = t.y; x[4*i+2] = t.z; x[4*i+3] = t.w;
    }
    float h1[HID];
    #pragma unroll
    for (int j = 0; j < HID; ++j) {
        float a = 0.f;
        #pragma unroll
        for (int i = 0; i < NES; ++i) a += x[i] * w1[i * HID + j];
        h1[j] = silu_f(b1[j] + a);
    }
    float h2[HID];
    #pragma unroll
    for (int j = 0; j < HID; ++j) {
        float a = 0.f;
        #pragma unroll
        for (int i = 0; i < HID; ++i) a += h1[i] * w2[i * HID + j];
        h2[j] = silu_f(b2[j] + a);
    }
    const QT* q = qn + (size_t)c * OUTD;
    #pragma unroll 1
    for (int h = 0; h < HEADS; ++h) {
        float wacc = 0.0f;
        #pragma unroll 1
        for (int jj = 0; jj < HEAD_DIM; ++jj) {
            const int j = h * HEAD_DIM + jj;
            float a = 0.f;
            #pragma unroll
            for (int i = 0; i < HID; ++i) a += h2[i] * w3[i * OUTD + j];
            wacc += (b3[j] + a) * loadQ(q + j);
        }
        const float Wv = wacc * ISQRTD;
        Wbuf[(size_t)e * HEADS + h] = Wv;
        atomicMax(&segmax[c * HEADS + h], fenc(Wv));
    }
}

__global__ __launch_bounds__(256) void ex_denom_kernel(
    const int* __restrict__ center, const unsigned* __restrict__ segmax,
    float* __restrict__ Wbuf, float* __restrict__ denom) {
    const int t = blockIdx.x * 256 + threadIdx.x;
    if (t >= N_EDGES * HEADS) return;
    const int e = t >> 4;
    const int h = t & 15;
    const int c = center[e];
    const float m  = fdec(segmax[c * HEADS + h]);
    const float ex = __expf(Wbuf[t] - m);
    Wbuf[t] = ex;
    atomicAdd(&denom[c * HEADS + h], ex);
}

__global__ __launch_bounds__(256) void attn_kernel(
    const int* __restrict__ center, float* __restrict__ Wbuf,
    const float* __restrict__ denom) {
    const int t = blockIdx.x * 256 + threadIdx.x;
    if (t >= N_EDGES * HEADS) return;
    const int e = t >> 4;
    const int h = t & 15;
    Wbuf[t] = Wbuf[t] / denom[center[e] * HEADS + h];
}

__global__ __launch_bounds__(256) void scatter4_kernel(
    const int* __restrict__ center, const float* __restrict__ edge_feat,
    const float* __restrict__ attn, float* __restrict__ out) {
    const int t = blockIdx.x * 256 + threadIdx.x;
    if (t >= N_EDGES * (EDGE_DIM / 4)) return;
    const int e  = t / (EDGE_DIM / 4);
    const int cg = t - e * (EDGE_DIM / 4);
    const int c  = center[e];
    const float4 f = *(const float4*)(edge_feat + (size_t)e * EDGE_DIM + cg * 4);
    const float* arow = attn + (size_t)e * HEADS;
    const float vals[4] = {f.x, f.y, f.z, f.w};
    #pragma unroll
    for (int k = 0; k < 4; ++k) {
        const int col = cg * 4 + k;
        const int h = headOf(col);
        atomicAdd(out + (size_t)c * EDGE_DIM + col, vals[k] * arow[h]);
    }
}

extern "C" void kernel_launch(void* const* d_in, const int* in_sizes, int n_in,
                              void* d_out, int out_size, void* d_ws, size_t ws_size,
                              hipStream_t stream) {
    const int*   edge_index = (const int*)d_in[0];
    const float* edge_feat  = (const float*)d_in[1];
    const float* node_attrs = (const float*)d_in[2];
    const float* q_w1 = (const float*)d_in[3];
    const float* q_b1 = (const float*)d_in[4];
    const float* q_w2 = (const float*)d_in[5];
    const float* q_b2 = (const float*)d_in[6];
    const float* q_w3 = (const float*)d_in[7];
    const float* q_b3 = (const float*)d_in[8];
    const float* k_w1 = (const float*)d_in[9];
    const float* k_b1 = (const float*)d_in[10];
    const float* k_w2 = (const float*)d_in[11];
    const float* k_b2 = (const float*)d_in[12];
    const float* k_w3 = (const float*)d_in[13];
    const float* k_b3 = (const float*)d_in[14];
    const int* center = edge_index;
    float* out = (float*)d_out;

    const size_t szQ    = (size_t)N_NODES * OUTD * sizeof(float);          // 102.4 MB
    const size_t szPf   = (size_t)N_NODES * HID * HEADS * sizeof(float);   // 204.8 MB
    const size_t szPb   = szPf / 2;
    const size_t szS    = (size_t)N_NODES * HEADS * sizeof(float);         //   3.2 MB
    const size_t szW    = (size_t)N_EDGES * HEADS * sizeof(float);         //  25.6 MB
    const size_t szDen  = (size_t)N_NODES * HEADS * sizeof(float);
    const size_t szT    = (NES * HID + HID * HID) * sizeof(float);

    const int qmlp2Grid   = (N_NODES + NPB_Q - 1) / NPB_Q;   // 3125
    const int pGrid3      = (N_NODES + NPB_P - 1) / NPB_P;   // 2000
    const int edgeGrid    = (N_EDGES + 255) / 256;
    const int nodeGrid256 = (N_NODES + 255) / 256;
    const int gatherGrid  = (N_NODES + 3) / 4;
    const int ehGrid      = (N_EDGES * HEADS + 255) / 256;

    const bool pathF32  = ws_size >= szQ + szPf + szS + szT;
    const bool pathBf16 = ws_size >= szQ + szPb + szS + szT;

    if (pathF32 || pathBf16) {
        // Layout: [Qn | Pn | Sn | w1T | w2T]. After pcompute3, Qn region is
        // reused for [Wbuf | counts | incl | rowStart | cursor | blockSums | edgeList | nodeOf].
        char* base = (char*)d_ws;
        float* Qn = (float*)base;
        char* pP  = base + szQ;
        const size_t szP = pathF32 ? szPf : szPb;
        char* pS  = pP + szP;
        float* Sn  = (float*)pS;
        float* w1T = (float*)(pS + szS);
        float* w2T = w1T + NES * HID;

        float* Wbuf     = (float*)base;                      // aliases Qn (dead)
        int*   counts   = (int*)(base + szW);
        int*   incl     = counts + N_NODES;
        int*   rowStart = incl + N_NODES;                    // N_NODES+1
        int*   cursor   = rowStart + N_NODES + 1;
        int*   blockSums= cursor + N_NODES;
        int*   edgeList = blockSums + ((NSB + 63) & ~63);
        int*   nodeOf   = edgeList + N_EDGES;

        prep_kernel<<<16, 256, 0, stream>>>(k_w1, k_w2, w1T, w2T);
        qmlp2_kernel<<<qmlp2Grid, 256, 0, stream>>>(
            node_attrs, q_w1, q_b1, q_w2, q_b2, q_w3, q_b3, Qn);

        if (pathF32) {
            float* Pn = (float*)pP;
            pcompute3_kernel<float><<<pGrid3, 256, 0, stream>>>(Qn, k_w3, k_b3, Pn, Sn);
        } else {
            __hip_bfloat16* Pn = (__hip_bfloat16*)pP;
            pcompute3_kernel<__hip_bfloat16><<<pGrid3, 256, 0, stream>>>(Qn, k_w3, k_b3, Pn, Sn);
        }

        zero_counts_kernel<<<nodeGrid256, 256, 0, stream>>>(counts);
        hist_kernel<<<edgeGrid, 256, 0, stream>>>(center, counts);
        scan1_kernel<<<NSB, SCAN_B, 0, stream>>>(counts, incl, blockSums);
        scan2_kernel<<<1, 64, 0, stream>>>(blockSums);
        scan3_kernel<<<NSB, SCAN_B, 0, stream>>>(counts, incl, blockSums, rowStart, cursor);
        fill_kernel<<<edgeGrid, 256, 0, stream>>>(center, cursor, edgeList, nodeOf);

        if (pathF32) {
            float* Pn = (float*)pP;
            wpass2_kernel<float><<<edgeGrid, 256, 0, stream>>>(
                edgeList, nodeOf, edge_feat, w1T, k_b1, w2T, k_b2, Pn, Sn, Wbuf);
        } else {
            __hip_bfloat16* Pn = (__hip_bfloat16*)pP;
            wpass2_kernel<__hip_bfloat16><<<edgeGrid, 256, 0, stream>>>(
                edgeList, nodeOf, edge_feat, w1T, k_b1, w2T, k_b2, Pn, Sn, Wbuf);
        }

        gather2_kernel<<<gatherGrid, 256, 0, stream>>>(rowStart, edgeList, edge_feat, Wbuf, out);
        return;
    }

    // ---------------- fallback: atomic pipeline (small ws) -------------------
    char* p = (char*)d_ws;
    float*    Wbuf   = (float*)p;    p += szW;
    float*    denom  = (float*)p;    p += szDen;
    unsigned* segmax = (unsigned*)p; p += szDen;
    const size_t fbase = (size_t)(p - (char*)d_ws);
    const bool qf32 = ws_size >= fbase + szQ;

    const int initGrid    = (N_NODES * EDGE_DIM + 255) / 256;
    const int scatterGrid = (N_EDGES * (EDGE_DIM / 4) + 255) / 256;
    const int qmlpGrid    = (N_NODES + 3) / 4;

    init_kernel<<<initGrid, 256, 0, stream>>>(out, denom, segmax);
    if (qf32) {
        float* qn = (float*)p;
        qmlp_kernel<float><<<qmlpGrid, 256, 0, stream>>>(
            node_attrs, q_w1, q_b1, q_w2, q_b2, q_w3, q_b3, qn);
        kmlp_kernel<float><<<edgeGrid, 256, 0, stream>>>(
            center, edge_feat, k_w1, k_b1, k_w2, k_b2, k_w3, k_b3, qn, Wbuf, segmax);
    } else {
        __hip_bfloat16* qn = (__hip_bfloat16*)p;
        qmlp_kernel<__hip_bfloat16><<<qmlpGrid, 256, 0, stream>>>(
            node_attrs, q_w1, q_b1, q_w2, q_b2, q_w3, q_b3, qn);
        kmlp_kernel<__hip_bfloat16><<<edgeGrid, 256, 0, stream>>>(
            center, edge_feat, k_w1, k_b1, k_w2, k_b2, k_w3, k_b3, qn, Wbuf, segmax);
    }
    ex_denom_kernel<<<ehGrid, 256, 0, stream>>>(center, segmax, Wbuf, denom);
    attn_kernel<<<ehGrid, 256, 0, stream>>>(center, Wbuf, denom);
    scatter4_kernel<<<scatterGrid, 256, 0, stream>>>(center, edge_feat, Wbuf, out);
}

// Round 7
// 525.003 us; speedup vs baseline: 5.2369x; 1.3191x over previous
//
#include <hip/hip_runtime.h>
#include <hip/hip_bf16.h>

constexpr int N_NODES  = 50000;
constexpr int N_EDGES  = 400000;
constexpr int EDGE_DIM = 144;
constexpr int HEADS    = 16;
constexpr int HEAD_DIM = 32;
constexpr int OUTD     = 512;   // HEADS*HEAD_DIM
constexpr int HID      = 64;
constexpr int NES      = 16;
constexpr int NNS      = 64;
constexpr int SCAN_B   = 512;
constexpr int NSB      = (N_NODES + SCAN_B - 1) / SCAN_B;   // 98
constexpr int NPB_A    = 64;    // nodes per block, papply
#define ISQRTD 0.17677669529663687f

__device__ __forceinline__ float silu_f(float x) {
    return x / (1.0f + __expf(-x));
}

__device__ __forceinline__ unsigned fenc(float f) {
    unsigned u = __float_as_uint(f);
    return (u & 0x80000000u) ? ~u : (u | 0x80000000u);
}
__device__ __forceinline__ float fdec(unsigned m) {
    unsigned u = (m & 0x80000000u) ? (m ^ 0x80000000u) : ~m;
    return __uint_as_float(u);
}

__device__ __forceinline__ int headOf(int col) {
    return (col < 16) ? col : ((col < 64) ? (col - 16) / 3 : (col - 64) / 5);
}

__device__ __forceinline__ void storeQ(float* p, float v) { *p = v; }
__device__ __forceinline__ void storeQ(__hip_bfloat16* p, float v) { *p = __float2bfloat16(v); }
__device__ __forceinline__ float loadQ(const float* p) { return *p; }
__device__ __forceinline__ float loadQ(const __hip_bfloat16* p) { return __bfloat162float(*p); }

// -------- prep: transpose k_w1 (16x64 -> 64x16) and k_w2 (64x64) -------------
__global__ __launch_bounds__(256) void prep_kernel(
    const float* __restrict__ w1, const float* __restrict__ w2,
    float* __restrict__ w1T, float* __restrict__ w2T) {
    int t = blockIdx.x * 256 + threadIdx.x;
    if (t < NES * HID) {
        int i = t / HID, j = t % HID;
        w1T[j * NES + i] = w1[t];
    }
    if (t < HID * HID) {
        int i = t / HID, j = t % HID;
        w2T[j * HID + i] = w2[t];
    }
}

// -------- mbuild: M[hg][i][j][hl], C0[hg][i][hl], Mb[h][j], c1[h] ------------
// M[h][i][j] = sum_d kw3[i,h*32+d]*qw3[j,h*32+d]
__global__ __launch_bounds__(256) void mbuild_kernel(
    const float* __restrict__ qw3, const float* __restrict__ qb3,
    const float* __restrict__ kw3, const float* __restrict__ kb3,
    float* __restrict__ M, float* __restrict__ C0,
    float* __restrict__ Mb, float* __restrict__ c1) {
    const int b = blockIdx.x, t = threadIdx.x;
    if (b < 256) {                     // M: 65536 entries
        const int o  = b * 256 + t;
        const int hl = o & 3, j = (o >> 2) & 63, i = (o >> 8) & 63, hg = o >> 14;
        const int h  = hg * 4 + hl;
        const float* ka = kw3 + (size_t)i * OUTD + h * HEAD_DIM;
        const float* qa = qw3 + (size_t)j * OUTD + h * HEAD_DIM;
        float s = 0.f;
        #pragma unroll
        for (int d = 0; d < HEAD_DIM; ++d) s += ka[d] * qa[d];
        M[o] = s;
    } else if (b < 260) {              // C0: 1024 entries, layout [hg][i][hl]
        const int o  = (b - 256) * 256 + t;
        const int hl = o & 3, i = (o >> 2) & 63, hg = o >> 8;
        const int h  = hg * 4 + hl;
        float s = 0.f;
        #pragma unroll
        for (int d = 0; d < HEAD_DIM; ++d)
            s += kw3[(size_t)i * OUTD + h * HEAD_DIM + d] * qb3[h * HEAD_DIM + d];
        C0[o] = s;
    } else if (b < 264) {              // Mb: [h][j]
        const int o = (b - 260) * 256 + t;
        const int h = o >> 6, j = o & 63;
        float s = 0.f;
        #pragma unroll
        for (int d = 0; d < HEAD_DIM; ++d)
            s += kb3[h * HEAD_DIM + d] * qw3[(size_t)j * OUTD + h * HEAD_DIM + d];
        Mb[o] = s;
    } else {                           // c1: 16
        if (t < HEADS) {
            float s = 0.f;
            #pragma unroll
            for (int d = 0; d < HEAD_DIM; ++d)
                s += kb3[t * HEAD_DIM + d] * qb3[t * HEAD_DIM + d];
            c1[t] = s;
        }
    }
}

// -------- h2q: Q-MLP layers 1-2 per node + Sn = h2.Mb + c1 -------------------
__global__ __launch_bounds__(256) void h2q_kernel(
    const float* __restrict__ node_attrs,
    const float* __restrict__ w1, const float* __restrict__ b1,
    const float* __restrict__ w2, const float* __restrict__ b2,
    const float* __restrict__ Mb, const float* __restrict__ c1,
    float* __restrict__ h2buf, float* __restrict__ Sn) {
    __shared__ float xs[4][NNS];
    __shared__ float h1s[4][HID];
    __shared__ float h2s[4][HID];
    __shared__ float Mbs[HEADS][65];   // pad 65: (h*65+x)%32 = (h+x)%32 -> <=2-way
    __shared__ float c1s[HEADS];
    const int t = threadIdx.x, wid = t >> 6, lane = t & 63;
    for (int o = t; o < HEADS * HID; o += 256) Mbs[o >> 6][o & 63] = Mb[o];
    if (t < HEADS) c1s[t] = c1[t];

    const int n = blockIdx.x * 4 + wid;
    const bool act = n < N_NODES;
    xs[wid][lane] = act ? node_attrs[(size_t)n * NNS + lane] : 0.0f;
    __syncthreads();

    float a = b1[lane];
    #pragma unroll
    for (int i = 0; i < NNS; ++i) a += xs[wid][i] * w1[i * HID + lane];
    h1s[wid][lane] = silu_f(a);
    __syncthreads();

    float a2 = b2[lane];
    #pragma unroll
    for (int i = 0; i < HID; ++i) a2 += h1s[wid][i] * w2[i * HID + lane];
    const float h2v = silu_f(a2);
    h2s[wid][lane] = h2v;
    if (act) h2buf[(size_t)n * HID + lane] = h2v;
    __syncthreads();

    // Sn: lane = (q,h); 16-FMA partial + xor-reduce over q
    const int h = lane & 15, q = lane >> 4;
    float s = 0.f;
    #pragma unroll
    for (int jj = 0; jj < 16; ++jj) s += h2s[wid][q * 16 + jj] * Mbs[h][q * 16 + jj];
    s += __shfl_xor(s, 16);
    s += __shfl_xor(s, 32);
    if (act && lane < HEADS) Sn[(size_t)n * HEADS + lane] = s + c1s[lane];
}

// -------- papply: P[n][hg][i][hl] = h2.Mreg + C0 (persistent M regs) ---------
__global__ __launch_bounds__(256) void papply_kernel(
    const float* __restrict__ h2buf, const float* __restrict__ M,
    const float* __restrict__ C0, float* __restrict__ Pn) {
    const int t  = threadIdx.x;
    const int hg = blockIdx.y;
    const int i  = t >> 2, hl = t & 3;

    float Mreg[HID];
    const float* msrc = M + (size_t)hg * 16384 + i * 256 + hl;
    #pragma unroll
    for (int j = 0; j < HID; ++j) Mreg[j] = msrc[j * 4];
    const float c0 = C0[hg * 256 + t];

    __shared__ float h2s[4][HID];
    const int n0 = blockIdx.x * NPB_A;
    #pragma unroll 1
    for (int s4 = 0; s4 < NPB_A / 4; ++s4) {
        const int nb = n0 + s4 * 4;
        const int nl = nb + (t >> 6);
        const float v = (nl < N_NODES) ? h2buf[(size_t)nl * HID + (t & 63)] : 0.f;
        __syncthreads();
        h2s[t >> 6][t & 63] = v;
        __syncthreads();
        #pragma unroll 1
        for (int mm = 0; mm < 4; ++mm) {
            const int n = nb + mm;
            if (n >= N_NODES) break;
            float acc0 = c0, acc1 = 0.f;
            #pragma unroll
            for (int j = 0; j < HID; j += 2) {
                acc0 += h2s[mm][j]     * Mreg[j];
                acc1 += h2s[mm][j + 1] * Mreg[j + 1];
            }
            Pn[(size_t)n * 1024 + hg * 256 + t] = acc0 + acc1;
        }
    }
}

// -------- CSR build ----------------------------------------------------------
__global__ __launch_bounds__(256) void zero_counts_kernel(int* __restrict__ counts) {
    int t = blockIdx.x * 256 + threadIdx.x;
    if (t < N_NODES) counts[t] = 0;
}
__global__ __launch_bounds__(256) void hist_kernel(const int* __restrict__ center,
                                                   int* __restrict__ counts) {
    int e = blockIdx.x * 256 + threadIdx.x;
    if (e < N_EDGES) atomicAdd(&counts[center[e]], 1);
}
__global__ __launch_bounds__(SCAN_B) void scan1_kernel(
    const int* __restrict__ counts, int* __restrict__ incl, int* __restrict__ blockSums) {
    __shared__ int sm[SCAN_B];
    const int gid = blockIdx.x * SCAN_B + threadIdx.x;
    sm[threadIdx.x] = (gid < N_NODES) ? counts[gid] : 0;
    __syncthreads();
    #pragma unroll 1
    for (int off = 1; off < SCAN_B; off <<= 1) {
        int t = (threadIdx.x >= off) ? sm[threadIdx.x - off] : 0;
        __syncthreads();
        sm[threadIdx.x] += t;
        __syncthreads();
    }
    if (gid < N_NODES) incl[gid] = sm[threadIdx.x];
    if (threadIdx.x == SCAN_B - 1) blockSums[blockIdx.x] = sm[threadIdx.x];
}
__global__ void scan2_kernel(int* __restrict__ blockSums) {
    if (threadIdx.x == 0 && blockIdx.x == 0) {
        int run = 0;
        for (int i = 0; i < NSB; ++i) { int t = blockSums[i]; blockSums[i] = run; run += t; }
    }
}
__global__ __launch_bounds__(SCAN_B) void scan3_kernel(
    const int* __restrict__ counts, const int* __restrict__ incl,
    const int* __restrict__ blockSums, int* __restrict__ rowStart,
    int* __restrict__ cursor) {
    const int gid = blockIdx.x * SCAN_B + threadIdx.x;
    if (gid < N_NODES) {
        const int excl = incl[gid] - counts[gid] + blockSums[blockIdx.x];
        rowStart[gid] = excl;
        cursor[gid]   = excl;
    }
    if (gid == 0) rowStart[N_NODES] = N_EDGES;
}
__global__ __launch_bounds__(256) void fill_kernel(const int* __restrict__ center,
                                                   int* __restrict__ cursor,
                                                   int* __restrict__ edgeList,
                                                   int* __restrict__ nodeOf) {
    int e = blockIdx.x * 256 + threadIdx.x;
    if (e < N_EDGES) {
        const int c = center[e];
        int pos = atomicAdd(&cursor[c], 1);
        edgeList[pos] = e;
        nodeOf[pos]   = c;
    }
}

// -------- W-pass (CSR slot order, new P layout) ------------------------------
__global__ __launch_bounds__(256) void wpass3_kernel(
    const int* __restrict__ edgeList, const int* __restrict__ nodeOf,
    const float* __restrict__ edge_feat,
    const float* __restrict__ w1T, const float* __restrict__ b1,
    const float* __restrict__ w2T, const float* __restrict__ b2,
    const float* __restrict__ Pn, const float* __restrict__ Sn,
    float* __restrict__ Wbuf) {
    const int p = blockIdx.x * 256 + threadIdx.x;
    if (p >= N_EDGES) return;
    const int e = edgeList[p];
    const int c = nodeOf[p];

    float x[NES];
    const float4* ef4 = reinterpret_cast<const float4*>(edge_feat + (size_t)e * EDGE_DIM);
    #pragma unroll
    for (int i = 0; i < NES / 4; ++i) {
        float4 t = ef4[i];
        x[4*i+0] = t.x; x[4*i+1] = t.y; x[4*i+2] = t.z; x[4*i+3] = t.w;
    }

    float h1[HID];
    #pragma unroll
    for (int j = 0; j < HID; ++j) {
        float a = b1[j];
        #pragma unroll
        for (int i = 0; i < NES; ++i) a += x[i] * w1T[j * NES + i];
        h1[j] = silu_f(a);
    }

    float wacc[HEADS];
    {
        const float4* s4 = (const float4*)(Sn + (size_t)c * HEADS);
        #pragma unroll
        for (int k = 0; k < 4; ++k) {
            float4 v = s4[k];
            wacc[4*k+0] = v.x; wacc[4*k+1] = v.y; wacc[4*k+2] = v.z; wacc[4*k+3] = v.w;
        }
    }

    const float* prow = Pn + (size_t)c * 1024;
    #pragma unroll 2
    for (int j = 0; j < HID; ++j) {
        float a = b2[j];
        #pragma unroll
        for (int i = 0; i < HID; ++i) a += h1[i] * w2T[j * HID + i];
        const float h2 = silu_f(a);
        #pragma unroll
        for (int hg = 0; hg < 4; ++hg) {
            const float4 pv = *(const float4*)(prow + hg * 256 + j * 4);
            wacc[hg*4+0] += h2 * pv.x;
            wacc[hg*4+1] += h2 * pv.y;
            wacc[hg*4+2] += h2 * pv.z;
            wacc[hg*4+3] += h2 * pv.w;
        }
    }

    float4* wrow = (float4*)(Wbuf + (size_t)p * HEADS);
    #pragma unroll
    for (int k = 0; k < 4; ++k) {
        wrow[k] = make_float4(wacc[4*k+0] * ISQRTD, wacc[4*k+1] * ISQRTD,
                              wacc[4*k+2] * ISQRTD, wacc[4*k+3] * ISQRTD);
    }
}

// -------- node gather: softmax + weighted sum, atomic-free -------------------
__global__ __launch_bounds__(256) void gather2_kernel(
    const int* __restrict__ rowStart, const int* __restrict__ edgeList,
    const float* __restrict__ edge_feat, const float* __restrict__ Wbuf,
    float* __restrict__ out) {
    const int wid  = threadIdx.x >> 6;
    const int lane = threadIdx.x & 63;
    const int n = blockIdx.x * 4 + wid;
    if (n >= N_NODES) return;
    const int rs = rowStart[n];
    const int d  = rowStart[n + 1] - rs;

    const int c0 = lane, c1 = lane + 64, c2 = lane + 128;
    const int h0 = headOf(c0);
    const int h1 = headOf(c1);
    const int h2 = (c2 < EDGE_DIM) ? headOf(c2) : 0;

    float acc0 = 0.f, acc1 = 0.f, acc2 = 0.f;
    if (d > 0) {
        const int hh  = lane & 15;
        const int sub = lane >> 4;
        float m = -3.0e38f;
        for (int i = sub; i < d; i += 4)
            m = fmaxf(m, Wbuf[(size_t)(rs + i) * HEADS + hh]);
        m = fmaxf(m, __shfl_xor(m, 16));
        m = fmaxf(m, __shfl_xor(m, 32));
        float s = 0.f;
        for (int i = sub; i < d; i += 4)
            s += __expf(Wbuf[(size_t)(rs + i) * HEADS + hh] - m);
        s += __shfl_xor(s, 16);
        s += __shfl_xor(s, 32);
        const float rden = 1.0f / s;

        for (int i = 0; i < d; ++i) {
            const int e = edgeList[rs + i];
            const float aL = __expf(Wbuf[(size_t)(rs + i) * HEADS + hh] - m) * rden;
            const float a0 = __shfl(aL, h0);
            const float a1 = __shfl(aL, h1);
            const float a2 = __shfl(aL, h2);
            const float* fr = edge_feat + (size_t)e * EDGE_DIM;
            acc0 += fr[c0] * a0;
            acc1 += fr[c1] * a1;
            if (c2 < EDGE_DIM) acc2 += fr[c2] * a2;
        }
    }
    float* orow = out + (size_t)n * EDGE_DIM;
    orow[c0] = acc0;
    orow[c1] = acc1;
    if (c2 < EDGE_DIM) orow[c2] = acc2;
}

// ==================== fallback-only kernels (small workspace) ================
template <typename QT>
__global__ __launch_bounds__(256) void qmlp_kernel(
    const float* __restrict__ node_attrs,
    const float* __restrict__ w1, const float* __restrict__ b1,
    const float* __restrict__ w2, const float* __restrict__ b2,
    const float* __restrict__ w3, const float* __restrict__ b3,
    QT* __restrict__ qn) {
    __shared__ float xs[4][NNS];
    __shared__ float hs[4][HID];
    const int wid  = threadIdx.x >> 6;
    const int lane = threadIdx.x & 63;
    const int node = blockIdx.x * 4 + wid;
    const bool act = node < N_NODES;

    xs[wid][lane] = act ? node_attrs[(size_t)node * NNS + lane] : 0.0f;
    __syncthreads();
    float a = b1[lane];
    #pragma unroll
    for (int i = 0; i < NNS; ++i) a += xs[wid][i] * w1[i * HID + lane];
    a = silu_f(a);
    hs[wid][lane] = a;
    __syncthreads();
    float a2 = b2[lane];
    #pragma unroll
    for (int i = 0; i < HID; ++i) a2 += hs[wid][i] * w2[i * HID + lane];
    a2 = silu_f(a2);
    __syncthreads();
    xs[wid][lane] = a2;
    __syncthreads();
    if (act) {
        #pragma unroll 1
        for (int j8 = 0; j8 < 8; ++j8) {
            const int col = j8 * 64 + lane;
            float acc = b3[col];
            #pragma unroll
            for (int i = 0; i < HID; ++i) acc += xs[wid][i] * w3[i * OUTD + col];
            storeQ(qn + (size_t)node * OUTD + col, acc);
        }
    }
}

__global__ __launch_bounds__(256) void init_kernel(float* __restrict__ out,
                                                   float* __restrict__ denom,
                                                   unsigned* __restrict__ segmax) {
    int t = blockIdx.x * 256 + threadIdx.x;
    if (t < N_NODES * EDGE_DIM) out[t] = 0.0f;
    if (t < N_NODES * HEADS) {
        denom[t]  = 0.0f;
        segmax[t] = 0u;
    }
}

template <typename QT>
__global__ __launch_bounds__(256) void kmlp_kernel(
    const int* __restrict__ center, const float* __restrict__ edge_feat,
    const float* __restrict__ w1, const float* __restrict__ b1,
    const float* __restrict__ w2, const float* __restrict__ b2,
    const float* __restrict__ w3, const float* __restrict__ b3,
    const QT* __restrict__ qn, float* __restrict__ Wbuf,
    unsigned* __restrict__ segmax) {
    const int e = blockIdx.x * 256 + threadIdx.x;
    if (e >= N_EDGES) return;
    const int c = center[e];
    float x[NES];
    const float4* ef4 = reinterpret_cast<const float4*>(edge_feat + (size_t)e * EDGE_DIM);
    #pragma unroll
    for (int i = 0; i < NES / 4; ++i) {
        float4 t = ef4[i];
        x[4*i+0] = t.x; x[4*i+1] = t.y; x[4*i+2] = t.z; x[4*i+3] = t.w;
    }
    float h1[HID];
    #pragma unroll
    for (int j = 0; j < HID; ++j) {
        float a = 0.f;
        #pragma unroll
        for (int i = 0; i < NES; ++i) a += x[i] * w1[i * HID + j];
        h1[j] = silu_f(b1[j] + a);
    }
    float h2[HID];
    #pragma unroll
    for (int j = 0; j < HID; ++j) {
        float a = 0.f;
        #pragma unroll
        for (int i = 0; i < HID; ++i) a += h1[i] * w2[i * HID + j];
        h2[j] = silu_f(b2[j] + a);
    }
    const QT* q = qn + (size_t)c * OUTD;
    #pragma unroll 1
    for (int h = 0; h < HEADS; ++h) {
        float wacc = 0.0f;
        #pragma unroll 1
        for (int jj = 0; jj < HEAD_DIM; ++jj) {
            const int j = h * HEAD_DIM + jj;
            float a = 0.f;
            #pragma unroll
            for (int i = 0; i < HID; ++i) a += h2[i] * w3[i * OUTD + j];
            wacc += (b3[j] + a) * loadQ(q + j);
        }
        const float Wv = wacc * ISQRTD;
        Wbuf[(size_t)e * HEADS + h] = Wv;
        atomicMax(&segmax[c * HEADS + h], fenc(Wv));
    }
}

__global__ __launch_bounds__(256) void ex_denom_kernel(
    const int* __restrict__ center, const unsigned* __restrict__ segmax,
    float* __restrict__ Wbuf, float* __restrict__ denom) {
    const int t = blockIdx.x * 256 + threadIdx.x;
    if (t >= N_EDGES * HEADS) return;
    const int e = t >> 4;
    const int h = t & 15;
    const int c = center[e];
    const float m  = fdec(segmax[c * HEADS + h]);
    const float ex = __expf(Wbuf[t] - m);
    Wbuf[t] = ex;
    atomicAdd(&denom[c * HEADS + h], ex);
}

__global__ __launch_bounds__(256) void attn_kernel(
    const int* __restrict__ center, float* __restrict__ Wbuf,
    const float* __restrict__ denom) {
    const int t = blockIdx.x * 256 + threadIdx.x;
    if (t >= N_EDGES * HEADS) return;
    const int e = t >> 4;
    const int h = t & 15;
    Wbuf[t] = Wbuf[t] / denom[center[e] * HEADS + h];
}

__global__ __launch_bounds__(256) void scatter4_kernel(
    const int* __restrict__ center, const float* __restrict__ edge_feat,
    const float* __restrict__ attn, float* __restrict__ out) {
    const int t = blockIdx.x * 256 + threadIdx.x;
    if (t >= N_EDGES * (EDGE_DIM / 4)) return;
    const int e  = t / (EDGE_DIM / 4);
    const int cg = t - e * (EDGE_DIM / 4);
    const int c  = center[e];
    const float4 f = *(const float4*)(edge_feat + (size_t)e * EDGE_DIM + cg * 4);
    const float* arow = attn + (size_t)e * HEADS;
    const float vals[4] = {f.x, f.y, f.z, f.w};
    #pragma unroll
    for (int k = 0; k < 4; ++k) {
        const int col = cg * 4 + k;
        const int h = headOf(col);
        atomicAdd(out + (size_t)c * EDGE_DIM + col, vals[k] * arow[h]);
    }
}

extern "C" void kernel_launch(void* const* d_in, const int* in_sizes, int n_in,
                              void* d_out, int out_size, void* d_ws, size_t ws_size,
                              hipStream_t stream) {
    const int*   edge_index = (const int*)d_in[0];
    const float* edge_feat  = (const float*)d_in[1];
    const float* node_attrs = (const float*)d_in[2];
    const float* q_w1 = (const float*)d_in[3];
    const float* q_b1 = (const float*)d_in[4];
    const float* q_w2 = (const float*)d_in[5];
    const float* q_b2 = (const float*)d_in[6];
    const float* q_w3 = (const float*)d_in[7];
    const float* q_b3 = (const float*)d_in[8];
    const float* k_w1 = (const float*)d_in[9];
    const float* k_b1 = (const float*)d_in[10];
    const float* k_w2 = (const float*)d_in[11];
    const float* k_b2 = (const float*)d_in[12];
    const float* k_w3 = (const float*)d_in[13];
    const float* k_b3 = (const float*)d_in[14];
    const int* center = edge_index;
    float* out = (float*)d_out;

    const size_t szP   = (size_t)N_NODES * HID * HEADS * sizeof(float);  // 204.8 MB
    const size_t szH2  = (size_t)N_NODES * HID * sizeof(float);          //  12.8 MB
    const size_t szS   = (size_t)N_NODES * HEADS * sizeof(float);        //   3.2 MB
    const size_t szW   = (size_t)N_EDGES * HEADS * sizeof(float);        //  25.6 MB
    const size_t szM   = (size_t)HID * HID * HEADS * sizeof(float);      // 256 KB
    const size_t szMisc= (1024 + 1024 + 64 + NES * HID + HID * HID) * sizeof(float);
    const size_t szCSR = ((size_t)4 * N_NODES + N_NODES + 1 + 256 + 2 * N_EDGES) * sizeof(int);

    const int h2qGrid     = (N_NODES + 3) / 4;              // 12500
    const dim3 papGrid((N_NODES + NPB_A - 1) / NPB_A, 4);   // (782, 4)
    const int edgeGrid    = (N_EDGES + 255) / 256;
    const int nodeGrid256 = (N_NODES + 255) / 256;
    const int gatherGrid  = (N_NODES + 3) / 4;
    const int ehGrid      = (N_EDGES * HEADS + 255) / 256;

    const size_t need = szP + szH2 + szS + szW + szM + szMisc + szCSR + 4096;

    if (ws_size >= need) {
        char* p = (char*)d_ws;
        float* Pn    = (float*)p;  p += szP;
        float* h2buf = (float*)p;  p += szH2;
        float* Sn    = (float*)p;  p += szS;
        float* Wbuf  = (float*)p;  p += szW;
        float* Mmat  = (float*)p;  p += szM;
        float* C0    = (float*)p;  p += 1024 * sizeof(float);
        float* Mb    = (float*)p;  p += 1024 * sizeof(float);
        float* c1v   = (float*)p;  p += 64 * sizeof(float);
        float* w1T   = (float*)p;  p += NES * HID * sizeof(float);
        float* w2T   = (float*)p;  p += HID * HID * sizeof(float);
        int* counts   = (int*)p;
        int* incl     = counts + N_NODES;
        int* rowStart = incl + N_NODES;          // N_NODES+1
        int* cursor   = rowStart + N_NODES + 1;
        int* blockSums= cursor + N_NODES;
        int* edgeList = blockSums + 256;
        int* nodeOf   = edgeList + N_EDGES;

        prep_kernel<<<16, 256, 0, stream>>>(k_w1, k_w2, w1T, w2T);
        mbuild_kernel<<<265, 256, 0, stream>>>(q_w3, q_b3, k_w3, k_b3, Mmat, C0, Mb, c1v);
        h2q_kernel<<<h2qGrid, 256, 0, stream>>>(
            node_attrs, q_w1, q_b1, q_w2, q_b2, Mb, c1v, h2buf, Sn);
        papply_kernel<<<papGrid, 256, 0, stream>>>(h2buf, Mmat, C0, Pn);

        zero_counts_kernel<<<nodeGrid256, 256, 0, stream>>>(counts);
        hist_kernel<<<edgeGrid, 256, 0, stream>>>(center, counts);
        scan1_kernel<<<NSB, SCAN_B, 0, stream>>>(counts, incl, blockSums);
        scan2_kernel<<<1, 64, 0, stream>>>(blockSums);
        scan3_kernel<<<NSB, SCAN_B, 0, stream>>>(counts, incl, blockSums, rowStart, cursor);
        fill_kernel<<<edgeGrid, 256, 0, stream>>>(center, cursor, edgeList, nodeOf);

        wpass3_kernel<<<edgeGrid, 256, 0, stream>>>(
            edgeList, nodeOf, edge_feat, w1T, k_b1, w2T, k_b2, Pn, Sn, Wbuf);
        gather2_kernel<<<gatherGrid, 256, 0, stream>>>(rowStart, edgeList, edge_feat, Wbuf, out);
        return;
    }

    // ---------------- fallback: atomic pipeline (small ws) -------------------
    const size_t szQ   = (size_t)N_NODES * OUTD * sizeof(float);
    char* p = (char*)d_ws;
    float*    Wbuf   = (float*)p;    p += szW;
    float*    denom  = (float*)p;    p += szS;
    unsigned* segmax = (unsigned*)p; p += szS;
    const size_t fbase = (size_t)(p - (char*)d_ws);
    const bool qf32 = ws_size >= fbase + szQ;

    const int initGrid    = (N_NODES * EDGE_DIM + 255) / 256;
    const int scatterGrid = (N_EDGES * (EDGE_DIM / 4) + 255) / 256;
    const int qmlpGrid    = (N_NODES + 3) / 4;

    init_kernel<<<initGrid, 256, 0, stream>>>(out, denom, segmax);
    if (qf32) {
        float* qn = (float*)p;
        qmlp_kernel<float><<<qmlpGrid, 256, 0, stream>>>(
            node_attrs, q_w1, q_b1, q_w2, q_b2, q_w3, q_b3, qn);
        kmlp_kernel<float><<<edgeGrid, 256, 0, stream>>>(
            center, edge_feat, k_w1, k_b1, k_w2, k_b2, k_w3, k_b3, qn, Wbuf, segmax);
    } else {
        __hip_bfloat16* qn = (__hip_bfloat16*)p;
        qmlp_kernel<__hip_bfloat16><<<qmlpGrid, 256, 0, stream>>>(
            node_attrs, q_w1, q_b1, q_w2, q_b2, q_w3, q_b3, qn);
        kmlp_kernel<__hip_bfloat16><<<edgeGrid, 256, 0, stream>>>(
            center, edge_feat, k_w1, k_b1, k_w2, k_b2, k_w3, k_b3, qn, Wbuf, segmax);
    }
    ex_denom_kernel<<<ehGrid, 256, 0, stream>>>(center, segmax, Wbuf, denom);
    attn_kernel<<<ehGrid, 256, 0, stream>>>(center, Wbuf, denom);
    scatter4_kernel<<<scatterGrid, 256, 0, stream>>>(center, edge_feat, Wbuf, out);
}